// Round 1
// baseline (713.910 us; speedup 1.0000x reference)
//
#include <hip/hip_runtime.h>

// ARMAConv x2 GNN: N=40000, E=640000, F_IN=512, HID=128, NCLS=64
#define F_IN 512
#define HID 128
#define NCLS 64

// ---------------- degree / norm ----------------
__global__ __launch_bounds__(256) void deg_kernel(const int* __restrict__ dst,
                                                  float* __restrict__ deg, int E) {
    int i = blockIdx.x * 256 + threadIdx.x;
    if (i < E) atomicAdd(&deg[dst[i]], 1.0f);
}

__global__ __launch_bounds__(256) void dinv_kernel(const float* __restrict__ deg,
                                                   float* __restrict__ dinv, int n) {
    int i = blockIdx.x * 256 + threadIdx.x;
    if (i < n) {
        float d = deg[i];
        dinv[i] = d > 0.f ? rsqrtf(d) : 0.f;
    }
}

// ---------------- fp32 tiled GEMM: out[M][BN] = A[M][K] @ W[K][BN] (+bias) ----------------
template <int BN>
__global__ __launch_bounds__(256) void gemm_kernel(const float* __restrict__ A,
                                                   const float* __restrict__ W,
                                                   const float* __restrict__ bias,
                                                   float* __restrict__ out,
                                                   int M, int K) {
    constexpr int BM = 64;
    constexpr int BK = 16;
    constexpr int TN = BN / 16;          // 8 (BN=128) or 4 (BN=64)
    constexpr int TM = 4;
    constexpr int NW = (BK * BN) / 1024; // float4 W-loads per thread: 2 or 1

    __shared__ float As[BK][BM + 1];
    __shared__ float Ws[BK][BN];

    const int tid = threadIdx.x;
    const int m0 = blockIdx.x * BM;      // M=40000 divides into 625 blocks of 64 exactly
    const int rowb = (tid >> 4) * TM;
    const int colb = (tid & 15) * TN;

    const int am = tid >> 2;             // 0..63
    const int ak = (tid & 3) << 2;       // 0,4,8,12

    float acc[TM][TN];
#pragma unroll
    for (int i = 0; i < TM; ++i)
#pragma unroll
        for (int j = 0; j < TN; ++j) acc[i][j] = 0.f;

    for (int kb = 0; kb < K; kb += BK) {
        float4 av = *reinterpret_cast<const float4*>(&A[(size_t)(m0 + am) * K + kb + ak]);
        float4 wv[NW];
#pragma unroll
        for (int l = 0; l < NW; ++l) {
            int idx = tid * 4 + l * 1024;
            int k = idx / BN;
            int c = idx % BN;
            wv[l] = *reinterpret_cast<const float4*>(&W[(size_t)(kb + k) * BN + c]);
        }
        __syncthreads();  // previous tile's compute done
        As[ak + 0][am] = av.x;
        As[ak + 1][am] = av.y;
        As[ak + 2][am] = av.z;
        As[ak + 3][am] = av.w;
#pragma unroll
        for (int l = 0; l < NW; ++l) {
            int idx = tid * 4 + l * 1024;
            int k = idx / BN;
            int c = idx % BN;
            *reinterpret_cast<float4*>(&Ws[k][c]) = wv[l];
        }
        __syncthreads();  // tile visible
#pragma unroll
        for (int kk = 0; kk < BK; ++kk) {
            float a[TM], b[TN];
#pragma unroll
            for (int i = 0; i < TM; ++i) a[i] = As[kk][rowb + i];
#pragma unroll
            for (int j = 0; j < TN; ++j) b[j] = Ws[kk][colb + j];
#pragma unroll
            for (int i = 0; i < TM; ++i)
#pragma unroll
                for (int j = 0; j < TN; ++j) acc[i][j] = fmaf(a[i], b[j], acc[i][j]);
        }
    }

#pragma unroll
    for (int j = 0; j < TN; ++j) {
        float bv = bias ? bias[colb + j] : 0.f;
#pragma unroll
        for (int i = 0; i < TM; ++i) {
            out[(size_t)(m0 + rowb + i) * BN + colb + j] = acc[i][j] + bv;
        }
    }
}

// ---------------- edge scatter: agg[dst] += norm * h[src] ----------------
template <int F>
__global__ __launch_bounds__(256) void scatter_kernel(const int* __restrict__ src,
                                                      const int* __restrict__ dst,
                                                      const float* __restrict__ dinv,
                                                      const float* __restrict__ h,
                                                      float* __restrict__ agg, int E) {
    int gtid = blockIdx.x * 256 + threadIdx.x;
    int wave = gtid >> 6;
    int lane = threadIdx.x & 63;
    int nwaves = (gridDim.x * 256) >> 6;
    for (int e = wave; e < E; e += nwaves) {
        int s = src[e];
        int d = dst[e];
        float nrm = dinv[s] * dinv[d];
        const float* hrow = h + (size_t)s * F;
        float* arow = agg + (size_t)d * F;
#pragma unroll
        for (int f = lane; f < F; f += 64) {
            atomicAdd(&arow[f], nrm * hrow[f]);
        }
    }
}

// ---------------- out = relu(a + b) ----------------
__global__ __launch_bounds__(256) void add_relu_kernel(const float* __restrict__ a,
                                                       const float* __restrict__ b,
                                                       float* __restrict__ out, int n) {
    int i = blockIdx.x * 256 + threadIdx.x;
    if (i < n) out[i] = fmaxf(a[i] + b[i], 0.f);
}

extern "C" void kernel_launch(void* const* d_in, const int* in_sizes, int n_in,
                              void* d_out, int out_size, void* d_ws, size_t ws_size,
                              hipStream_t stream) {
    const float* x   = (const float*)d_in[0];
    const float* W1i = (const float*)d_in[1];
    const float* W1r = (const float*)d_in[2];
    const float* b1  = (const float*)d_in[3];
    const float* W2i = (const float*)d_in[4];
    const float* W2r = (const float*)d_in[5];
    const float* b2  = (const float*)d_in[6];
    const int*   ei  = (const int*)d_in[7];

    const int E = in_sizes[7] / 2;
    const int M = in_sizes[0] / F_IN;  // 40000
    const int* src = ei;
    const int* dst = ei + E;

    float* ws = (float*)d_ws;
    float* deg  = ws;                               // 40000
    float* dinv = ws + 40960;                       // 40000
    float* h1   = ws + 81920;                       // M*HID
    float* r1   = h1 + (size_t)M * HID;             // M*HID
    float* agg1 = r1 + (size_t)M * HID;             // M*HID
    float* out1 = agg1 + (size_t)M * HID;           // M*HID
    // layer-2 buffers alias dead layer-1 buffers (each needs only M*NCLS <= M*HID)
    float* h2   = h1;
    float* r2   = r1;
    float* agg2 = agg1;
    float* outp = (float*)d_out;

    // degrees + normalization
    hipMemsetAsync(deg, 0, (size_t)M * sizeof(float), stream);
    deg_kernel<<<(E + 255) / 256, 256, 0, stream>>>(dst, deg, E);
    dinv_kernel<<<(M + 255) / 256, 256, 0, stream>>>(deg, dinv, M);

    // layer 1
    gemm_kernel<HID><<<M / 64, 256, 0, stream>>>(x, W1i, nullptr, h1, M, F_IN);
    gemm_kernel<HID><<<M / 64, 256, 0, stream>>>(x, W1r, b1, r1, M, F_IN);
    hipMemsetAsync(agg1, 0, (size_t)M * HID * sizeof(float), stream);
    scatter_kernel<HID><<<4096, 256, 0, stream>>>(src, dst, dinv, h1, agg1, E);
    add_relu_kernel<<<(M * HID + 255) / 256, 256, 0, stream>>>(agg1, r1, out1, M * HID);

    // layer 2
    gemm_kernel<NCLS><<<M / 64, 256, 0, stream>>>(out1, W2i, nullptr, h2, M, HID);
    gemm_kernel<NCLS><<<M / 64, 256, 0, stream>>>(out1, W2r, b2, r2, M, HID);
    hipMemsetAsync(agg2, 0, (size_t)M * NCLS * sizeof(float), stream);
    scatter_kernel<NCLS><<<4096, 256, 0, stream>>>(src, dst, dinv, h2, agg2, E);
    add_relu_kernel<<<(M * NCLS + 255) / 256, 256, 0, stream>>>(agg2, r2, outp, M * NCLS);
}

// Round 3
// 453.508 us; speedup vs baseline: 1.5742x; 1.5742x over previous
//
#include <hip/hip_runtime.h>

// ARMAConv x2 GNN: N=40000, E=640000, F_IN=512, HID=128, NCLS=64
#define F_IN 512
#define HID 128
#define NCLS 64

// ---------------- degree count (int) ----------------
__global__ __launch_bounds__(256) void count_kernel(const int* __restrict__ dst,
                                                    int* __restrict__ cnt, int E) {
    int i = blockIdx.x * 256 + threadIdx.x;
    if (i < E) atomicAdd(&cnt[dst[i]], 1);
}

__global__ __launch_bounds__(256) void dinv_kernel(const int* __restrict__ cnt,
                                                   float* __restrict__ dinv, int n) {
    int i = blockIdx.x * 256 + threadIdx.x;
    if (i < n) {
        int d = cnt[i];
        dinv[i] = d > 0 ? rsqrtf((float)d) : 0.f;
    }
}

// ---------------- hierarchical exclusive scan over cnt -> rowptr ----------------
__global__ __launch_bounds__(1024) void scan1_kernel(const int* __restrict__ cnt,
                                                     int* __restrict__ rowptr,
                                                     int* __restrict__ bsum, int n) {
    __shared__ int s[1024];
    int tid = threadIdx.x;
    int i = blockIdx.x * 1024 + tid;
    int v = (i < n) ? cnt[i] : 0;
    s[tid] = v;
    __syncthreads();
    for (int off = 1; off < 1024; off <<= 1) {
        int t = (tid >= off) ? s[tid - off] : 0;
        __syncthreads();
        s[tid] += t;
        __syncthreads();
    }
    if (i < n) rowptr[i] = s[tid] - v;  // exclusive within block
    if (tid == 1023) bsum[blockIdx.x] = s[1023];
}

__global__ void scan2_kernel(int* __restrict__ bsum, int nb) {
    if (threadIdx.x == 0 && blockIdx.x == 0) {
        int run = 0;
        for (int b = 0; b < nb; ++b) {
            int t = bsum[b];
            bsum[b] = run;
            run += t;
        }
    }
}

__global__ __launch_bounds__(1024) void scan3_kernel(int* __restrict__ rowptr,
                                                     const int* __restrict__ bsum, int n) {
    int i = blockIdx.x * 1024 + threadIdx.x;
    if (i < n) rowptr[i] += bsum[blockIdx.x];
}

// ---------------- CSR fill: bucket edges by dst, precompute per-edge norm ----------------
__global__ __launch_bounds__(256) void fill_kernel(const int* __restrict__ src,
                                                   const int* __restrict__ dst,
                                                   const int* __restrict__ rowptr,
                                                   int* __restrict__ fill,
                                                   const float* __restrict__ dinv,
                                                   int* __restrict__ csrc,
                                                   float* __restrict__ cnrm, int E) {
    int e = blockIdx.x * 256 + threadIdx.x;
    if (e < E) {
        int s = src[e];
        int d = dst[e];
        int pos = rowptr[d] + atomicAdd(&fill[d], 1);
        csrc[pos] = s;
        cnrm[pos] = dinv[s] * dinv[d];
    }
}

// ---------------- fp32 tiled GEMM: out[M][BN] = A[M][K] @ W[K][BN] (+bias) ----------------
template <int BN>
__global__ __launch_bounds__(256) void gemm_kernel(const float* __restrict__ A,
                                                   const float* __restrict__ W,
                                                   const float* __restrict__ bias,
                                                   float* __restrict__ out,
                                                   int M, int K) {
    constexpr int BM = 64;
    constexpr int BK = 16;
    constexpr int TN = BN / 16;
    constexpr int TM = 4;
    constexpr int NW = (BK * BN) / 1024;

    __shared__ float As[BK][BM + 1];
    __shared__ float Ws[BK][BN];

    const int tid = threadIdx.x;
    const int m0 = blockIdx.x * BM;
    const int rowb = (tid >> 4) * TM;
    const int colb = (tid & 15) * TN;

    const int am = tid >> 2;
    const int ak = (tid & 3) << 2;

    float acc[TM][TN];
#pragma unroll
    for (int i = 0; i < TM; ++i)
#pragma unroll
        for (int j = 0; j < TN; ++j) acc[i][j] = 0.f;

    for (int kb = 0; kb < K; kb += BK) {
        float4 av = *reinterpret_cast<const float4*>(&A[(size_t)(m0 + am) * K + kb + ak]);
        float4 wv[NW];
#pragma unroll
        for (int l = 0; l < NW; ++l) {
            int idx = tid * 4 + l * 1024;
            int k = idx / BN;
            int c = idx % BN;
            wv[l] = *reinterpret_cast<const float4*>(&W[(size_t)(kb + k) * BN + c]);
        }
        __syncthreads();
        As[ak + 0][am] = av.x;
        As[ak + 1][am] = av.y;
        As[ak + 2][am] = av.z;
        As[ak + 3][am] = av.w;
#pragma unroll
        for (int l = 0; l < NW; ++l) {
            int idx = tid * 4 + l * 1024;
            int k = idx / BN;
            int c = idx % BN;
            *reinterpret_cast<float4*>(&Ws[k][c]) = wv[l];
        }
        __syncthreads();
#pragma unroll
        for (int kk = 0; kk < BK; ++kk) {
            float a[TM], b[TN];
#pragma unroll
            for (int i = 0; i < TM; ++i) a[i] = As[kk][rowb + i];
#pragma unroll
            for (int j = 0; j < TN; ++j) b[j] = Ws[kk][colb + j];
#pragma unroll
            for (int i = 0; i < TM; ++i)
#pragma unroll
                for (int j = 0; j < TN; ++j) acc[i][j] = fmaf(a[i], b[j], acc[i][j]);
        }
    }

#pragma unroll
    for (int j = 0; j < TN; ++j) {
        float bv = bias ? bias[colb + j] : 0.f;
#pragma unroll
        for (int i = 0; i < TM; ++i) {
            out[(size_t)(m0 + rowb + i) * BN + colb + j] = acc[i][j] + bv;
        }
    }
}

// ---------------- CSR gather + fused epilogue: out[v] = relu(sum_e nrm*h[src] + r[v]) ----------------
template <int F>
__global__ __launch_bounds__(256) void gather_kernel(const int* __restrict__ rowptr,
                                                     const int* __restrict__ cnt,
                                                     const int* __restrict__ csrc,
                                                     const float* __restrict__ cnrm,
                                                     const float* __restrict__ h,
                                                     const float* __restrict__ r,
                                                     float* __restrict__ out, int n) {
    int wid = (blockIdx.x * 256 + threadIdx.x) >> 6;
    int lane = threadIdx.x & 63;
    if (wid >= n) return;
    const int s0 = rowptr[wid];
    const int len = cnt[wid];
    if (F == 128) {
        const float2* hp = reinterpret_cast<const float2*>(h);
        float2 acc = {0.f, 0.f};
        for (int k = 0; k < len; ++k) {
            int s = csrc[s0 + k];
            float nr = cnrm[s0 + k];
            float2 hv = hp[(size_t)s * 64 + lane];
            acc.x = fmaf(nr, hv.x, acc.x);
            acc.y = fmaf(nr, hv.y, acc.y);
        }
        float2 rv = reinterpret_cast<const float2*>(r)[(size_t)wid * 64 + lane];
        float2 o;
        o.x = fmaxf(acc.x + rv.x, 0.f);
        o.y = fmaxf(acc.y + rv.y, 0.f);
        reinterpret_cast<float2*>(out)[(size_t)wid * 64 + lane] = o;
    } else {
        float acc = 0.f;
        for (int k = 0; k < len; ++k) {
            int s = csrc[s0 + k];
            float nr = cnrm[s0 + k];
            acc = fmaf(nr, h[(size_t)s * F + lane], acc);
        }
        float rv = r[(size_t)wid * F + lane];
        out[(size_t)wid * F + lane] = fmaxf(acc + rv, 0.f);
    }
}

extern "C" void kernel_launch(void* const* d_in, const int* in_sizes, int n_in,
                              void* d_out, int out_size, void* d_ws, size_t ws_size,
                              hipStream_t stream) {
    const float* x   = (const float*)d_in[0];
    const float* W1i = (const float*)d_in[1];
    const float* W1r = (const float*)d_in[2];
    const float* b1  = (const float*)d_in[3];
    const float* W2i = (const float*)d_in[4];
    const float* W2r = (const float*)d_in[5];
    const float* b2  = (const float*)d_in[6];
    const int*   ei  = (const int*)d_in[7];

    const int E = in_sizes[7] / 2;
    const int M = in_sizes[0] / F_IN;  // 40000
    const int* src = ei;
    const int* dst = ei + E;

    char* w = (char*)d_ws;
    int*   cnt    = (int*)w;    w += 40960 * 4;
    int*   rowptr = (int*)w;    w += 40960 * 4;
    int*   fill   = (int*)w;    w += 40960 * 4;
    float* dinv   = (float*)w;  w += 40960 * 4;
    int*   bsum   = (int*)w;    w += 256 * 4;
    int*   csrc   = (int*)w;    w += (size_t)E * 4;
    float* cnrm   = (float*)w;  w += (size_t)E * 4;
    float* h1     = (float*)w;  w += (size_t)M * HID * 4;
    float* r1     = (float*)w;  w += (size_t)M * HID * 4;
    float* out1   = (float*)w;  w += (size_t)M * HID * 4;
    float* h2     = h1;  // layer-2 buffers (M*NCLS) alias dead layer-1 buffers
    float* r2     = r1;
    float* outp   = (float*)d_out;

    const int nb = (M + 1023) / 1024;  // 40 scan blocks

    // ---- CSR build ----
    hipMemsetAsync(cnt, 0, (size_t)M * sizeof(int), stream);
    hipMemsetAsync(fill, 0, (size_t)M * sizeof(int), stream);
    count_kernel<<<(E + 255) / 256, 256, 0, stream>>>(dst, cnt, E);
    dinv_kernel<<<(M + 255) / 256, 256, 0, stream>>>(cnt, dinv, M);
    scan1_kernel<<<nb, 1024, 0, stream>>>(cnt, rowptr, bsum, M);
    scan2_kernel<<<1, 64, 0, stream>>>(bsum, nb);
    scan3_kernel<<<nb, 1024, 0, stream>>>(rowptr, bsum, M);
    fill_kernel<<<(E + 255) / 256, 256, 0, stream>>>(src, dst, rowptr, fill, dinv, csrc, cnrm, E);

    // ---- layer 1 ----
    gemm_kernel<HID><<<M / 64, 256, 0, stream>>>(x, W1i, nullptr, h1, M, F_IN);
    gemm_kernel<HID><<<M / 64, 256, 0, stream>>>(x, W1r, b1, r1, M, F_IN);
    gather_kernel<HID><<<(M * 64 + 255) / 256, 256, 0, stream>>>(rowptr, cnt, csrc, cnrm, h1, r1, out1, M);

    // ---- layer 2 ----
    gemm_kernel<NCLS><<<M / 64, 256, 0, stream>>>(out1, W2i, nullptr, h2, M, HID);
    gemm_kernel<NCLS><<<M / 64, 256, 0, stream>>>(out1, W2r, b2, r2, M, HID);
    gather_kernel<NCLS><<<(M * 64 + 255) / 256, 256, 0, stream>>>(rowptr, cnt, csrc, cnrm, h2, r2, outp, M);
}

// Round 4
// 270.744 us; speedup vs baseline: 2.6368x; 1.6750x over previous
//
#include <hip/hip_runtime.h>

// ARMAConv x2 GNN: N=40000, E=640000, F_IN=512, HID=128, NCLS=64
#define F_IN 512
#define HID 128
#define NCLS 64
#define MPAD 40064  // 313 * 128

typedef __bf16 bf16x8 __attribute__((ext_vector_type(8)));
typedef __bf16 bf16x4v __attribute__((ext_vector_type(4)));
typedef float f32x4 __attribute__((ext_vector_type(4)));

__device__ __forceinline__ float bf2f(unsigned short u) {
    unsigned v = (unsigned)u << 16;
    float f;
    __builtin_memcpy(&f, &v, 4);
    return f;
}

// ---------------- degree count ----------------
__global__ __launch_bounds__(256) void count_kernel(const int* __restrict__ dst,
                                                    int* __restrict__ cnt, int E) {
    int i = blockIdx.x * 256 + threadIdx.x;
    if (i < E) atomicAdd(&cnt[dst[i]], 1);
}

__global__ __launch_bounds__(256) void dinv_kernel(const int* __restrict__ cnt,
                                                   float* __restrict__ dinv, int n) {
    int i = blockIdx.x * 256 + threadIdx.x;
    if (i < n) {
        int d = cnt[i];
        dinv[i] = d > 0 ? rsqrtf((float)d) : 0.f;
    }
}

// ---------------- scan ----------------
__global__ __launch_bounds__(1024) void scan1_kernel(const int* __restrict__ cnt,
                                                     int* __restrict__ rowptr,
                                                     int* __restrict__ bsum, int n) {
    __shared__ int s[1024];
    int tid = threadIdx.x;
    int i = blockIdx.x * 1024 + tid;
    int v = (i < n) ? cnt[i] : 0;
    s[tid] = v;
    __syncthreads();
    for (int off = 1; off < 1024; off <<= 1) {
        int t = (tid >= off) ? s[tid - off] : 0;
        __syncthreads();
        s[tid] += t;
        __syncthreads();
    }
    if (i < n) rowptr[i] = s[tid] - v;
    if (tid == 1023) bsum[blockIdx.x] = s[1023];
}

__global__ void scan2_kernel(int* __restrict__ bsum, int nb) {
    if (threadIdx.x == 0 && blockIdx.x == 0) {
        int run = 0;
        for (int b = 0; b < nb; ++b) {
            int t = bsum[b];
            bsum[b] = run;
            run += t;
        }
    }
}

__global__ __launch_bounds__(1024) void scan3_kernel(int* __restrict__ rowptr,
                                                     const int* __restrict__ bsum, int n) {
    int i = blockIdx.x * 1024 + threadIdx.x;
    if (i < n) rowptr[i] += bsum[blockIdx.x];
}

// ---------------- CSR fill ----------------
__global__ __launch_bounds__(256) void fill_kernel(const int* __restrict__ src,
                                                   const int* __restrict__ dst,
                                                   const int* __restrict__ rowptr,
                                                   int* __restrict__ fill,
                                                   const float* __restrict__ dinv,
                                                   int* __restrict__ csrc,
                                                   float* __restrict__ cnrm, int E) {
    int e = blockIdx.x * 256 + threadIdx.x;
    if (e < E) {
        int s = src[e];
        int d = dst[e];
        int pos = rowptr[d] + atomicAdd(&fill[d], 1);
        csrc[pos] = s;
        cnrm[pos] = dinv[s] * dinv[d];
    }
}

// ---------------- fp32 -> bf16 cast (x4 vectorized) ----------------
__global__ __launch_bounds__(256) void cast_kernel(const float* __restrict__ in,
                                                   __bf16* __restrict__ out, long n4) {
    long i = (long)blockIdx.x * 256 + threadIdx.x;
    if (i < n4) {
        float4 v = *reinterpret_cast<const float4*>(in + i * 4);
        bf16x4v o;
        o[0] = (__bf16)v.x;
        o[1] = (__bf16)v.y;
        o[2] = (__bf16)v.z;
        o[3] = (__bf16)v.w;
        *reinterpret_cast<bf16x4v*>(out + i * 4) = o;
    }
}

// ---------------- weight prep: Wt[n][k] = bf16(W[k][n]), [Wi | Wr] concat ----------------
__global__ __launch_bounds__(256) void prep_w_kernel(const float* __restrict__ Wi,
                                                     const float* __restrict__ Wr,
                                                     __bf16* __restrict__ Wt,
                                                     int K, int NH) {
    int n = blockIdx.x;  // 0 .. 2*NH-1
    const float* Wsrc = (n < NH) ? Wi : Wr;
    int c = (n < NH) ? n : n - NH;
    for (int k = threadIdx.x; k < K; k += 256)
        Wt[(long)n * K + k] = (__bf16)Wsrc[(long)k * NH + c];
}

// ---------------- bf16 MFMA GEMM: H[Mp][NT] = A[Mp][K] @ Bt[NT][K]^T (+bias on cols>=NH) ----
// 128x64 block tile, 4 waves (32 rows each), BK=64, global_load_lds w16,
// XOR-swizzle (row&7)<<4: linear LDS dest + pre-swizzled global src + swizzled read.
template <int NT, int NH>
__global__ __launch_bounds__(256) void gemm_mfma(const __bf16* __restrict__ A,
                                                 const __bf16* __restrict__ Bt,
                                                 const float* __restrict__ bias,
                                                 __bf16* __restrict__ H, int K) {
    __shared__ char smem[24576];  // A tile [128][64]bf16 = 16KB, B tile [64][64]bf16 = 8KB
    const int tid = threadIdx.x;
    const int w = tid >> 6, l = tid & 63;
    const int lr = l & 15, lg = l >> 4;
    const long m0 = (long)blockIdx.x * 128;
    const int n0 = blockIdx.y * 64;
    const long Kb = (long)K * 2;  // row stride in bytes

    f32x4 acc[2][4] = {};

    // reader physical LDS offsets (swizzled)
    int a_off[2][2], b_off[2][4];
#pragma unroll
    for (int fm = 0; fm < 2; ++fm) {
        int r = w * 32 + fm * 16 + lr;
        int s = (r & 7) << 4;
#pragma unroll
        for (int kk = 0; kk < 2; ++kk)
            a_off[fm][kk] = r * 128 + ((kk * 64 + lg * 16) ^ s);
    }
#pragma unroll
    for (int fn = 0; fn < 4; ++fn) {
        int c = fn * 16 + lr;
        int s = (c & 7) << 4;
#pragma unroll
        for (int kk = 0; kk < 2; ++kk)
            b_off[kk][fn] = 16384 + c * 128 + ((kk * 64 + lg * 16) ^ s);
    }

    // staging: 24 wave-issues of 1KB; this thread's 6 issues (region r = w*6+j)
    const char* gsrc[6];
    char* ldst[6];
#pragma unroll
    for (int j = 0; j < 6; ++j) {
        int p = (w * 6 + j) * 1024 + l * 16;  // physical LDS byte this lane covers
        ldst[j] = smem + (w * 6 + j) * 1024;  // wave-uniform base (HW adds lane*16)
        if (p < 16384) {                      // A region (uniform per issue)
            int row = p >> 7;
            int loff = (p & 127) ^ ((row & 7) << 4);  // inverse-swizzled source
            gsrc[j] = (const char*)A + (m0 + row) * Kb + loff;
        } else {
            int q = p - 16384;
            int c = q >> 7;
            int loff = (q & 127) ^ ((c & 7) << 4);
            gsrc[j] = (const char*)Bt + (long)(n0 + c) * Kb + loff;
        }
    }

    const int nk = K >> 6;
    for (int kt = 0; kt < nk; ++kt) {
#pragma unroll
        for (int j = 0; j < 6; ++j) {
            __builtin_amdgcn_global_load_lds(
                (const __attribute__((address_space(1))) unsigned*)(const void*)(gsrc[j] + (long)kt * 128),
                (__attribute__((address_space(3))) unsigned*)(void*)ldst[j], 16, 0, 0);
        }
        __syncthreads();  // drains vmcnt -> tile ready
#pragma unroll
        for (int kk = 0; kk < 2; ++kk) {
            bf16x8 av[2], bv[4];
#pragma unroll
            for (int fm = 0; fm < 2; ++fm)
                av[fm] = *reinterpret_cast<const bf16x8*>(smem + a_off[fm][kk]);
#pragma unroll
            for (int fn = 0; fn < 4; ++fn)
                bv[fn] = *reinterpret_cast<const bf16x8*>(smem + b_off[kk][fn]);
#pragma unroll
            for (int fm = 0; fm < 2; ++fm)
#pragma unroll
                for (int fn = 0; fn < 4; ++fn)
                    acc[fm][fn] = __builtin_amdgcn_mfma_f32_16x16x32_bf16(
                        av[fm], bv[fn], acc[fm][fn], 0, 0, 0);
        }
        __syncthreads();  // all reads done before next overwrite
    }

    // epilogue: C/D layout col=lane&15, row=(lane>>4)*4+j  [m89-verified]
#pragma unroll
    for (int fn = 0; fn < 4; ++fn) {
        int col = n0 + fn * 16 + lr;
        float bvv = (col >= NH) ? bias[col - NH] : 0.f;
#pragma unroll
        for (int fm = 0; fm < 2; ++fm) {
            long row = m0 + w * 32 + fm * 16 + lg * 4;
#pragma unroll
            for (int j2 = 0; j2 < 4; ++j2)
                H[(row + j2) * NT + col] = (__bf16)(acc[fm][fn][j2] + bvv);
        }
    }
}

// ---------------- gather (F=128): out1b = bf16(relu(agg + r)), H interleaved [Mp][256] ----
__global__ __launch_bounds__(256) void gather128_kernel(const int* __restrict__ rowptr,
                                                        const int* __restrict__ cnt,
                                                        const int* __restrict__ csrc,
                                                        const float* __restrict__ cnrm,
                                                        const unsigned short* __restrict__ Hb,
                                                        __bf16* __restrict__ outb, int n) {
    int wid = (blockIdx.x * 256 + threadIdx.x) >> 6;
    int l = threadIdx.x & 63;
    if (wid >= n) return;
    int s0 = rowptr[wid], len = cnt[wid];
    float ax = 0.f, ay = 0.f;
    for (int k = 0; k < len; ++k) {
        int s = csrc[s0 + k];
        float nr = cnrm[s0 + k];
        unsigned v = *reinterpret_cast<const unsigned*>(Hb + (long)s * 256 + 2 * l);
        float h0, h1;
        {
            unsigned lo = v << 16, hi = v & 0xffff0000u;
            __builtin_memcpy(&h0, &lo, 4);
            __builtin_memcpy(&h1, &hi, 4);
        }
        ax = fmaf(nr, h0, ax);
        ay = fmaf(nr, h1, ay);
    }
    unsigned rv = *reinterpret_cast<const unsigned*>(Hb + (long)wid * 256 + 128 + 2 * l);
    float r0, r1;
    {
        unsigned lo = rv << 16, hi = rv & 0xffff0000u;
        __builtin_memcpy(&r0, &lo, 4);
        __builtin_memcpy(&r1, &hi, 4);
    }
    union { unsigned u; __bf16 b[2]; } pk;
    pk.b[0] = (__bf16)fmaxf(ax + r0, 0.f);
    pk.b[1] = (__bf16)fmaxf(ay + r1, 0.f);
    *reinterpret_cast<unsigned*>(&outb[(long)wid * 128 + 2 * l]) = pk.u;
}

// ---------------- gather (F=64): fp32 out = relu(agg + r), H2 interleaved [Mp][128] ----
__global__ __launch_bounds__(256) void gather64_kernel(const int* __restrict__ rowptr,
                                                       const int* __restrict__ cnt,
                                                       const int* __restrict__ csrc,
                                                       const float* __restrict__ cnrm,
                                                       const unsigned short* __restrict__ Hb,
                                                       float* __restrict__ out, int n) {
    int wid = (blockIdx.x * 256 + threadIdx.x) >> 6;
    int l = threadIdx.x & 63;
    if (wid >= n) return;
    int s0 = rowptr[wid], len = cnt[wid];
    float a = 0.f;
    for (int k = 0; k < len; ++k) {
        int s = csrc[s0 + k];
        float nr = cnrm[s0 + k];
        a = fmaf(nr, bf2f(Hb[(long)s * 128 + l]), a);
    }
    float r = bf2f(Hb[(long)wid * 128 + 64 + l]);
    out[(long)wid * 64 + l] = fmaxf(a + r, 0.f);
}

extern "C" void kernel_launch(void* const* d_in, const int* in_sizes, int n_in,
                              void* d_out, int out_size, void* d_ws, size_t ws_size,
                              hipStream_t stream) {
    const float* x   = (const float*)d_in[0];
    const float* W1i = (const float*)d_in[1];
    const float* W1r = (const float*)d_in[2];
    const float* b1  = (const float*)d_in[3];
    const float* W2i = (const float*)d_in[4];
    const float* W2r = (const float*)d_in[5];
    const float* b2  = (const float*)d_in[6];
    const int*   ei  = (const int*)d_in[7];

    const int E = in_sizes[7] / 2;
    const int M = in_sizes[0] / F_IN;  // 40000
    const int* src = ei;
    const int* dst = ei + E;

    char* w = (char*)d_ws;
    int*    cnt    = (int*)w;            w += 40960 * 4;
    int*    rowptr = (int*)w;            w += 40960 * 4;
    int*    fill   = (int*)w;            w += 40960 * 4;
    float*  dinv   = (float*)w;          w += 40960 * 4;
    int*    bsum   = (int*)w;            w += 4096;
    int*    csrc   = (int*)w;            w += (size_t)E * 4;
    float*  cnrm   = (float*)w;          w += (size_t)E * 4;
    __bf16* W1t    = (__bf16*)w;         w += 256 * 512 * 2;
    __bf16* W2t    = (__bf16*)w;         w += 128 * 128 * 2;
    __bf16* xb     = (__bf16*)w;         w += (size_t)MPAD * 512 * 2;  // 41MB
    __bf16* H1b    = (__bf16*)w;         w += (size_t)MPAD * 256 * 2;  // 20.5MB
    // aliases into dead xb region after GEMM1:
    __bf16* out1b  = xb;                                   // [MPAD][128] = 10.25MB
    __bf16* H2b    = xb + (size_t)MPAD * 128;              // [MPAD][128]
    float*  outp   = (float*)d_out;

    const int nb = (M + 1023) / 1024;

    // ---- CSR build ----
    hipMemsetAsync(cnt, 0, (size_t)M * sizeof(int), stream);
    hipMemsetAsync(fill, 0, (size_t)M * sizeof(int), stream);
    count_kernel<<<(E + 255) / 256, 256, 0, stream>>>(dst, cnt, E);
    dinv_kernel<<<(M + 255) / 256, 256, 0, stream>>>(cnt, dinv, M);
    scan1_kernel<<<nb, 1024, 0, stream>>>(cnt, rowptr, bsum, M);
    scan2_kernel<<<1, 64, 0, stream>>>(bsum, nb);
    scan3_kernel<<<nb, 1024, 0, stream>>>(rowptr, bsum, M);
    fill_kernel<<<(E + 255) / 256, 256, 0, stream>>>(src, dst, rowptr, fill, dinv, csrc, cnrm, E);

    // ---- input cast + weight prep ----
    cast_kernel<<<(int)(((long)M * F_IN / 4 + 255) / 256), 256, 0, stream>>>(
        x, xb, (long)M * F_IN / 4);
    prep_w_kernel<<<256, 256, 0, stream>>>(W1i, W1r, W1t, F_IN, HID);
    prep_w_kernel<<<128, 256, 0, stream>>>(W2i, W2r, W2t, HID, NCLS);

    // ---- layer 1: H1 = xb @ [W1i|W1r] (+b1 on cols>=128) ----
    gemm_mfma<256, 128><<<dim3(MPAD / 128, 4), 256, 0, stream>>>(xb, W1t, b1, H1b, F_IN);
    gather128_kernel<<<(M * 64 + 255) / 256, 256, 0, stream>>>(
        rowptr, cnt, csrc, cnrm, (const unsigned short*)H1b, out1b, M);

    // ---- layer 2: H2 = out1b @ [W2i|W2r] (+b2 on cols>=64) ----
    gemm_mfma<128, 64><<<dim3(MPAD / 128, 2), 256, 0, stream>>>(out1b, W2t, b2, H2b, HID);
    gather64_kernel<<<(M * 64 + 255) / 256, 256, 0, stream>>>(
        rowptr, cnt, csrc, cnrm, (const unsigned short*)H2b, outp, M);
}

// Round 5
// 189.744 us; speedup vs baseline: 3.7625x; 1.4269x over previous
//
#include <hip/hip_runtime.h>

// ARMAConv x2 GNN: N=40000, E=640000, F_IN=512, HID=128, NCLS=64
#define F_IN 512
#define HID 128
#define NCLS 64
#define MPAD 40064  // 313 * 128

typedef __bf16 bf16x8 __attribute__((ext_vector_type(8)));
typedef __bf16 bf16x4v __attribute__((ext_vector_type(4)));
typedef float f32x4 __attribute__((ext_vector_type(4)));

__device__ __forceinline__ float lo16(unsigned u) {
    unsigned x = u << 16;
    float f;
    __builtin_memcpy(&f, &x, 4);
    return f;
}
__device__ __forceinline__ float hi16(unsigned u) {
    unsigned x = u & 0xffff0000u;
    float f;
    __builtin_memcpy(&f, &x, 4);
    return f;
}
__device__ __forceinline__ float bf2f(unsigned short u) {
    return lo16((unsigned)u << 16 >> 16 << 16 | (unsigned)u << 16);  // not used hot
}

// ---------------- degree count ----------------
__global__ __launch_bounds__(256) void count_kernel(const int* __restrict__ dst,
                                                    int* __restrict__ cnt, int E) {
    int i = blockIdx.x * 256 + threadIdx.x;
    if (i < E) atomicAdd(&cnt[dst[i]], 1);
}

__global__ __launch_bounds__(256) void dinv_kernel(const int* __restrict__ cnt,
                                                   float* __restrict__ dinv, int n) {
    int i = blockIdx.x * 256 + threadIdx.x;
    if (i < n) {
        int d = cnt[i];
        dinv[i] = d > 0 ? rsqrtf((float)d) : 0.f;
    }
}

// ---------------- scan ----------------
__global__ __launch_bounds__(1024) void scan1_kernel(const int* __restrict__ cnt,
                                                     int* __restrict__ rowptr,
                                                     int* __restrict__ bsum, int n) {
    __shared__ int s[1024];
    int tid = threadIdx.x;
    int i = blockIdx.x * 1024 + tid;
    int v = (i < n) ? cnt[i] : 0;
    s[tid] = v;
    __syncthreads();
    for (int off = 1; off < 1024; off <<= 1) {
        int t = (tid >= off) ? s[tid - off] : 0;
        __syncthreads();
        s[tid] += t;
        __syncthreads();
    }
    if (i < n) rowptr[i] = s[tid] - v;
    if (tid == 1023) bsum[blockIdx.x] = s[1023];
}

__global__ void scan2_kernel(int* __restrict__ bsum, int nb) {
    if (threadIdx.x == 0 && blockIdx.x == 0) {
        int run = 0;
        for (int b = 0; b < nb; ++b) {
            int t = bsum[b];
            bsum[b] = run;
            run += t;
        }
    }
}

__global__ __launch_bounds__(1024) void scan3_kernel(int* __restrict__ rowptr,
                                                     const int* __restrict__ bsum, int n) {
    int i = blockIdx.x * 1024 + threadIdx.x;
    if (i < n) rowptr[i] += bsum[blockIdx.x];
}

// ---------------- CSR fill: packed {src, norm} per edge ----------------
__global__ __launch_bounds__(256) void fill_kernel(const int* __restrict__ src,
                                                   const int* __restrict__ dst,
                                                   const int* __restrict__ rowptr,
                                                   int* __restrict__ fill,
                                                   const float* __restrict__ dinv,
                                                   uint2* __restrict__ epk, int E) {
    int e = blockIdx.x * 256 + threadIdx.x;
    if (e < E) {
        int s = src[e];
        int d = dst[e];
        int pos = rowptr[d] + atomicAdd(&fill[d], 1);
        float nr = dinv[s] * dinv[d];
        unsigned nu;
        __builtin_memcpy(&nu, &nr, 4);
        epk[pos] = make_uint2((unsigned)s, nu);
    }
}

// ---------------- fp32 -> bf16 cast ----------------
__global__ __launch_bounds__(256) void cast_kernel(const float* __restrict__ in,
                                                   __bf16* __restrict__ out, long n4) {
    long i = (long)blockIdx.x * 256 + threadIdx.x;
    if (i < n4) {
        float4 v = *reinterpret_cast<const float4*>(in + i * 4);
        bf16x4v o;
        o[0] = (__bf16)v.x;
        o[1] = (__bf16)v.y;
        o[2] = (__bf16)v.z;
        o[3] = (__bf16)v.w;
        *reinterpret_cast<bf16x4v*>(out + i * 4) = o;
    }
}

// ---------------- weight prep ----------------
__global__ __launch_bounds__(256) void prep_w_kernel(const float* __restrict__ Wi,
                                                     const float* __restrict__ Wr,
                                                     __bf16* __restrict__ Wt,
                                                     int K, int NH) {
    int n = blockIdx.x;
    const float* Wsrc = (n < NH) ? Wi : Wr;
    int c = (n < NH) ? n : n - NH;
    for (int k = threadIdx.x; k < K; k += 256)
        Wt[(long)n * K + k] = (__bf16)Wsrc[(long)k * NH + c];
}

// ---------------- bf16 MFMA GEMM (unchanged from round 4) ----------------
template <int NT, int NH>
__global__ __launch_bounds__(256) void gemm_mfma(const __bf16* __restrict__ A,
                                                 const __bf16* __restrict__ Bt,
                                                 const float* __restrict__ bias,
                                                 __bf16* __restrict__ H, int K) {
    __shared__ char smem[24576];
    const int tid = threadIdx.x;
    const int w = tid >> 6, l = tid & 63;
    const int lr = l & 15, lg = l >> 4;
    const long m0 = (long)blockIdx.x * 128;
    const int n0 = blockIdx.y * 64;
    const long Kb = (long)K * 2;

    f32x4 acc[2][4] = {};

    int a_off[2][2], b_off[2][4];
#pragma unroll
    for (int fm = 0; fm < 2; ++fm) {
        int r = w * 32 + fm * 16 + lr;
        int s = (r & 7) << 4;
#pragma unroll
        for (int kk = 0; kk < 2; ++kk)
            a_off[fm][kk] = r * 128 + ((kk * 64 + lg * 16) ^ s);
    }
#pragma unroll
    for (int fn = 0; fn < 4; ++fn) {
        int c = fn * 16 + lr;
        int s = (c & 7) << 4;
#pragma unroll
        for (int kk = 0; kk < 2; ++kk)
            b_off[kk][fn] = 16384 + c * 128 + ((kk * 64 + lg * 16) ^ s);
    }

    const char* gsrc[6];
    char* ldst[6];
#pragma unroll
    for (int j = 0; j < 6; ++j) {
        int p = (w * 6 + j) * 1024 + l * 16;
        ldst[j] = smem + (w * 6 + j) * 1024;
        if (p < 16384) {
            int row = p >> 7;
            int loff = (p & 127) ^ ((row & 7) << 4);
            gsrc[j] = (const char*)A + (m0 + row) * Kb + loff;
        } else {
            int q = p - 16384;
            int c = q >> 7;
            int loff = (q & 127) ^ ((c & 7) << 4);
            gsrc[j] = (const char*)Bt + (long)(n0 + c) * Kb + loff;
        }
    }

    const int nk = K >> 6;
    for (int kt = 0; kt < nk; ++kt) {
#pragma unroll
        for (int j = 0; j < 6; ++j) {
            __builtin_amdgcn_global_load_lds(
                (const __attribute__((address_space(1))) unsigned*)(const void*)(gsrc[j] + (long)kt * 128),
                (__attribute__((address_space(3))) unsigned*)(void*)ldst[j], 16, 0, 0);
        }
        __syncthreads();
#pragma unroll
        for (int kk = 0; kk < 2; ++kk) {
            bf16x8 av[2], bv[4];
#pragma unroll
            for (int fm = 0; fm < 2; ++fm)
                av[fm] = *reinterpret_cast<const bf16x8*>(smem + a_off[fm][kk]);
#pragma unroll
            for (int fn = 0; fn < 4; ++fn)
                bv[fn] = *reinterpret_cast<const bf16x8*>(smem + b_off[kk][fn]);
#pragma unroll
            for (int fm = 0; fm < 2; ++fm)
#pragma unroll
                for (int fn = 0; fn < 4; ++fn)
                    acc[fm][fn] = __builtin_amdgcn_mfma_f32_16x16x32_bf16(
                        av[fm], bv[fn], acc[fm][fn], 0, 0, 0);
        }
        __syncthreads();
    }

#pragma unroll
    for (int fn = 0; fn < 4; ++fn) {
        int col = n0 + fn * 16 + lr;
        float bvv = (col >= NH) ? bias[col - NH] : 0.f;
#pragma unroll
        for (int fm = 0; fm < 2; ++fm) {
            long row = m0 + w * 32 + fm * 16 + lg * 4;
#pragma unroll
            for (int j2 = 0; j2 < 4; ++j2)
                H[(row + j2) * NT + col] = (__bf16)(acc[fm][fn][j2] + bvv);
        }
    }
}

// ---------------- gather F=128: quarter-wave (16 lanes x uint4), 4 edges in flight ----
__global__ __launch_bounds__(256) void gather128_kernel(const int* __restrict__ rowptr,
                                                        const int* __restrict__ cnt,
                                                        const uint2* __restrict__ epk,
                                                        const unsigned short* __restrict__ Hb,
                                                        __bf16* __restrict__ outb, int n) {
    int wid = (blockIdx.x * 256 + threadIdx.x) >> 6;
    int l = threadIdx.x & 63;
    if (wid >= n) return;
    const int s0 = rowptr[wid], len = cnt[wid];
    const int li = l & 15, q = l >> 4;

    int sv = 0;
    float nv = 0.f;
    if (l < len) {
        uint2 p = epk[s0 + l];
        sv = (int)p.x;
        nv = __uint_as_float(p.y);
    }
    const int m = len < 64 ? len : 64;
    const int T = (m + 3) >> 2;

    float a[8] = {};
#pragma unroll 2
    for (int t = 0; t < T; ++t) {
        int e = 4 * t + q;
        int s = __shfl(sv, e);
        float nr = __shfl(nv, e);
        uint4 v = *reinterpret_cast<const uint4*>(Hb + (size_t)s * 256 + 8 * li);
        a[0] = fmaf(nr, lo16(v.x), a[0]);
        a[1] = fmaf(nr, hi16(v.x), a[1]);
        a[2] = fmaf(nr, lo16(v.y), a[2]);
        a[3] = fmaf(nr, hi16(v.y), a[3]);
        a[4] = fmaf(nr, lo16(v.z), a[4]);
        a[5] = fmaf(nr, hi16(v.z), a[5]);
        a[6] = fmaf(nr, lo16(v.w), a[6]);
        a[7] = fmaf(nr, hi16(v.w), a[7]);
    }
    // tail (len > 64: essentially never for Poisson(16), but must be correct)
    for (int k = 64; k < len; ++k) {
        if (q == 0) {
            uint2 p = epk[s0 + k];
            int s = (int)p.x;
            float nr = __uint_as_float(p.y);
            uint4 v = *reinterpret_cast<const uint4*>(Hb + (size_t)s * 256 + 8 * li);
            a[0] = fmaf(nr, lo16(v.x), a[0]);
            a[1] = fmaf(nr, hi16(v.x), a[1]);
            a[2] = fmaf(nr, lo16(v.y), a[2]);
            a[3] = fmaf(nr, hi16(v.y), a[3]);
            a[4] = fmaf(nr, lo16(v.z), a[4]);
            a[5] = fmaf(nr, hi16(v.z), a[5]);
            a[6] = fmaf(nr, lo16(v.w), a[6]);
            a[7] = fmaf(nr, hi16(v.w), a[7]);
        }
    }
#pragma unroll
    for (int i = 0; i < 8; ++i) {
        a[i] += __shfl_xor(a[i], 16);
        a[i] += __shfl_xor(a[i], 32);
    }
    if (l < 16) {
        uint4 rv = *reinterpret_cast<const uint4*>(Hb + (size_t)wid * 256 + 128 + 8 * l);
        float r[8] = {lo16(rv.x), hi16(rv.x), lo16(rv.y), hi16(rv.y),
                      lo16(rv.z), hi16(rv.z), lo16(rv.w), hi16(rv.w)};
        union { uint4 v; __bf16 b[8]; } o;
#pragma unroll
        for (int i = 0; i < 8; ++i) o.b[i] = (__bf16)fmaxf(a[i] + r[i], 0.f);
        *reinterpret_cast<uint4*>(outb + (size_t)wid * 128 + 8 * l) = o.v;
    }
}

// ---------------- gather F=64: quarter-wave (16 lanes x uint2), fp32 out ----
__global__ __launch_bounds__(256) void gather64_kernel(const int* __restrict__ rowptr,
                                                       const int* __restrict__ cnt,
                                                       const uint2* __restrict__ epk,
                                                       const unsigned short* __restrict__ Hb,
                                                       float* __restrict__ out, int n) {
    int wid = (blockIdx.x * 256 + threadIdx.x) >> 6;
    int l = threadIdx.x & 63;
    if (wid >= n) return;
    const int s0 = rowptr[wid], len = cnt[wid];
    const int li = l & 15, q = l >> 4;

    int sv = 0;
    float nv = 0.f;
    if (l < len) {
        uint2 p = epk[s0 + l];
        sv = (int)p.x;
        nv = __uint_as_float(p.y);
    }
    const int m = len < 64 ? len : 64;
    const int T = (m + 3) >> 2;

    float a[4] = {};
#pragma unroll 2
    for (int t = 0; t < T; ++t) {
        int e = 4 * t + q;
        int s = __shfl(sv, e);
        float nr = __shfl(nv, e);
        uint2 v = *reinterpret_cast<const uint2*>(Hb + (size_t)s * 128 + 4 * li);
        a[0] = fmaf(nr, lo16(v.x), a[0]);
        a[1] = fmaf(nr, hi16(v.x), a[1]);
        a[2] = fmaf(nr, lo16(v.y), a[2]);
        a[3] = fmaf(nr, hi16(v.y), a[3]);
    }
    for (int k = 64; k < len; ++k) {
        if (q == 0) {
            uint2 p = epk[s0 + k];
            int s = (int)p.x;
            float nr = __uint_as_float(p.y);
            uint2 v = *reinterpret_cast<const uint2*>(Hb + (size_t)s * 128 + 4 * li);
            a[0] = fmaf(nr, lo16(v.x), a[0]);
            a[1] = fmaf(nr, hi16(v.x), a[1]);
            a[2] = fmaf(nr, lo16(v.y), a[2]);
            a[3] = fmaf(nr, hi16(v.y), a[3]);
        }
    }
#pragma unroll
    for (int i = 0; i < 4; ++i) {
        a[i] += __shfl_xor(a[i], 16);
        a[i] += __shfl_xor(a[i], 32);
    }
    if (l < 16) {
        uint2 rv = *reinterpret_cast<const uint2*>(Hb + (size_t)wid * 128 + 64 + 4 * l);
        float4 o;
        o.x = fmaxf(a[0] + lo16(rv.x), 0.f);
        o.y = fmaxf(a[1] + hi16(rv.x), 0.f);
        o.z = fmaxf(a[2] + lo16(rv.y), 0.f);
        o.w = fmaxf(a[3] + hi16(rv.y), 0.f);
        *reinterpret_cast<float4*>(out + (size_t)wid * 64 + 4 * l) = o;
    }
}

extern "C" void kernel_launch(void* const* d_in, const int* in_sizes, int n_in,
                              void* d_out, int out_size, void* d_ws, size_t ws_size,
                              hipStream_t stream) {
    const float* x   = (const float*)d_in[0];
    const float* W1i = (const float*)d_in[1];
    const float* W1r = (const float*)d_in[2];
    const float* b1  = (const float*)d_in[3];
    const float* W2i = (const float*)d_in[4];
    const float* W2r = (const float*)d_in[5];
    const float* b2  = (const float*)d_in[6];
    const int*   ei  = (const int*)d_in[7];

    const int E = in_sizes[7] / 2;
    const int M = in_sizes[0] / F_IN;  // 40000
    const int* src = ei;
    const int* dst = ei + E;

    char* w = (char*)d_ws;
    int*    cnt    = (int*)w;            w += 40960 * 4;
    int*    rowptr = (int*)w;            w += 40960 * 4;
    int*    fill   = (int*)w;            w += 40960 * 4;
    float*  dinv   = (float*)w;          w += 40960 * 4;
    int*    bsum   = (int*)w;            w += 4096;
    uint2*  epk    = (uint2*)w;          w += (size_t)E * 8;
    __bf16* W1t    = (__bf16*)w;         w += 256 * 512 * 2;
    __bf16* W2t    = (__bf16*)w;         w += 128 * 128 * 2;
    __bf16* xb     = (__bf16*)w;         w += (size_t)MPAD * 512 * 2;
    __bf16* H1b    = (__bf16*)w;         w += (size_t)MPAD * 256 * 2;
    __bf16* out1b  = xb;                                   // aliases dead xb
    __bf16* H2b    = xb + (size_t)MPAD * 128;
    float*  outp   = (float*)d_out;

    const int nb = (M + 1023) / 1024;

    // ---- CSR build ----
    hipMemsetAsync(cnt, 0, (size_t)M * sizeof(int), stream);
    hipMemsetAsync(fill, 0, (size_t)M * sizeof(int), stream);
    count_kernel<<<(E + 255) / 256, 256, 0, stream>>>(dst, cnt, E);
    dinv_kernel<<<(M + 255) / 256, 256, 0, stream>>>(cnt, dinv, M);
    scan1_kernel<<<nb, 1024, 0, stream>>>(cnt, rowptr, bsum, M);
    scan2_kernel<<<1, 64, 0, stream>>>(bsum, nb);
    scan3_kernel<<<nb, 1024, 0, stream>>>(rowptr, bsum, M);
    fill_kernel<<<(E + 255) / 256, 256, 0, stream>>>(src, dst, rowptr, fill, dinv, epk, E);

    // ---- input cast + weight prep ----
    cast_kernel<<<(int)(((long)M * F_IN / 4 + 255) / 256), 256, 0, stream>>>(
        x, xb, (long)M * F_IN / 4);
    prep_w_kernel<<<256, 256, 0, stream>>>(W1i, W1r, W1t, F_IN, HID);
    prep_w_kernel<<<128, 256, 0, stream>>>(W2i, W2r, W2t, HID, NCLS);

    // ---- layer 1 ----
    gemm_mfma<256, 128><<<dim3(MPAD / 128, 4), 256, 0, stream>>>(xb, W1t, b1, H1b, F_IN);
    gather128_kernel<<<(M * 64 + 255) / 256, 256, 0, stream>>>(
        rowptr, cnt, epk, (const unsigned short*)H1b, out1b, M);

    // ---- layer 2 ----
    gemm_mfma<128, 64><<<dim3(MPAD / 128, 2), 256, 0, stream>>>(out1b, W2t, b2, H2b, HID);
    gather64_kernel<<<(M * 64 + 255) / 256, 256, 0, stream>>>(
        rowptr, cnt, epk, (const unsigned short*)H2b, outp, M);
}

// Round 6
// 161.320 us; speedup vs baseline: 4.4254x; 1.1762x over previous
//
#include <hip/hip_runtime.h>

// ARMAConv x2 GNN: N=40000, E=640000, F_IN=512, HID=128, NCLS=64
#define F_IN 512
#define HID 128
#define NCLS 64
#define MPAD 40064  // 313 * 128

typedef __bf16 bf16x8 __attribute__((ext_vector_type(8)));
typedef float f32x4 __attribute__((ext_vector_type(4)));

__device__ __forceinline__ float lo16(unsigned u) {
    unsigned x = u << 16;
    float f;
    __builtin_memcpy(&f, &x, 4);
    return f;
}
__device__ __forceinline__ float hi16(unsigned u) {
    unsigned x = u & 0xffff0000u;
    float f;
    __builtin_memcpy(&f, &x, 4);
    return f;
}

// ---------------- degree count ----------------
__global__ __launch_bounds__(256) void count_kernel(const int* __restrict__ dst,
                                                    int* __restrict__ cnt, int E) {
    int i = blockIdx.x * 256 + threadIdx.x;
    if (i < E) atomicAdd(&cnt[dst[i]], 1);
}

__global__ __launch_bounds__(256) void dinv_kernel(const int* __restrict__ cnt,
                                                   float* __restrict__ dinv, int n) {
    int i = blockIdx.x * 256 + threadIdx.x;
    if (i < n) {
        int d = cnt[i];
        dinv[i] = d > 0 ? rsqrtf((float)d) : 0.f;
    }
}

// ---------------- scan ----------------
__global__ __launch_bounds__(1024) void scan1_kernel(const int* __restrict__ cnt,
                                                     int* __restrict__ rowptr,
                                                     int* __restrict__ bsum, int n) {
    __shared__ int s[1024];
    int tid = threadIdx.x;
    int i = blockIdx.x * 1024 + tid;
    int v = (i < n) ? cnt[i] : 0;
    s[tid] = v;
    __syncthreads();
    for (int off = 1; off < 1024; off <<= 1) {
        int t = (tid >= off) ? s[tid - off] : 0;
        __syncthreads();
        s[tid] += t;
        __syncthreads();
    }
    if (i < n) rowptr[i] = s[tid] - v;
    if (tid == 1023) bsum[blockIdx.x] = s[1023];
}

__global__ void scan2_kernel(int* __restrict__ bsum, int nb) {
    if (threadIdx.x == 0 && blockIdx.x == 0) {
        int run = 0;
        for (int b = 0; b < nb; ++b) {
            int t = bsum[b];
            bsum[b] = run;
            run += t;
        }
    }
}

__global__ __launch_bounds__(1024) void scan3_kernel(int* __restrict__ rowptr,
                                                     const int* __restrict__ bsum, int n) {
    int i = blockIdx.x * 1024 + threadIdx.x;
    if (i < n) rowptr[i] += bsum[blockIdx.x];
}

// ---------------- CSR fill: bump rowptr in place (becomes end-offsets) ----------------
__global__ __launch_bounds__(256) void fill_kernel(const int* __restrict__ src,
                                                   const int* __restrict__ dst,
                                                   int* __restrict__ rowptr,
                                                   const float* __restrict__ dinv,
                                                   uint2* __restrict__ epk, int E) {
    int e = blockIdx.x * 256 + threadIdx.x;
    if (e < E) {
        int s = src[e];
        int d = dst[e];
        int pos = atomicAdd(&rowptr[d], 1);
        float nr = dinv[s] * dinv[d];
        unsigned nu;
        __builtin_memcpy(&nu, &nr, 4);
        epk[pos] = make_uint2((unsigned)s, nu);
    }
}

// ---------------- weight prep ----------------
__global__ __launch_bounds__(256) void prep_w_kernel(const float* __restrict__ Wi,
                                                     const float* __restrict__ Wr,
                                                     __bf16* __restrict__ Wt,
                                                     int K, int NH) {
    int n = blockIdx.x;
    const float* Wsrc = (n < NH) ? Wi : Wr;
    int c = (n < NH) ? n : n - NH;
    for (int k = threadIdx.x; k < K; k += 256)
        Wt[(long)n * K + k] = (__bf16)Wsrc[(long)k * NH + c];
}

// ---------------- GEMM1 fused-cast: H[Mp][256] = bf16(A_f32[M][512]) @ Bt[256][512]^T ----
// 128x256 tile, 8 waves (4M x 2N), BK=64. A: fp32 reg-stage -> bf16 swizzled ds_write.
// B: global_load_lds w16, pre-swizzled source. XOR swizzle: byte ^ ((row&7)<<4).
__global__ __launch_bounds__(512) void gemm1_kernel(const float* __restrict__ A,
                                                    const __bf16* __restrict__ Bt,
                                                    const float* __restrict__ bias,
                                                    __bf16* __restrict__ H, int M) {
    __shared__ char smem[49152];  // A bf16 [128][64] @0 (16KB); B bf16 [256][64] @16KB (32KB)
    const int tid = threadIdx.x;
    const int w = tid >> 6, l = tid & 63;
    const int wm = w >> 1, wn = w & 1;    // 4 x 2 wave grid
    const int lr = l & 15, lg = l >> 4;
    const long m0 = (long)blockIdx.x * 128;

    f32x4 acc[2][8] = {};

    // A-stage mapping: thread covers row = tid>>2, k0 = (tid&3)*16 (16 fp32 -> 16 bf16)
    const int ar = tid >> 2;
    const int ak0 = (tid & 3) << 4;
    long arow_g = m0 + ar;
    if (arow_g >= M) arow_g = 0;  // clamp tail block (garbage rows never consumed)
    const float* aptr = A + arow_g * F_IN + ak0;
    const int asw = (ar & 7) << 4;
    char* adst0 = smem + ar * 128 + ((ak0 * 2) ^ asw);
    char* adst1 = smem + ar * 128 + ((ak0 * 2 + 16) ^ asw);

    // B-stage: 32 x 1KB issues, wave w does issues w*4..w*4+3
    const char* gsrc[4];
    char* ldst[4];
#pragma unroll
    for (int j = 0; j < 4; ++j) {
        int q = (w * 4 + j) * 1024 + l * 16;  // byte within B region
        ldst[j] = smem + 16384 + (w * 4 + j) * 1024;
        int c = q >> 7;
        int qb = q & 127;
        gsrc[j] = (const char*)Bt + (long)c * 1024 + (qb ^ ((c & 7) << 4));
    }

    // reader offsets
    int a_off[2][2], b_off[2][8];
#pragma unroll
    for (int fm = 0; fm < 2; ++fm) {
        int r = wm * 32 + fm * 16 + lr;
        int s = (r & 7) << 4;
#pragma unroll
        for (int kk = 0; kk < 2; ++kk)
            a_off[fm][kk] = r * 128 + ((kk * 64 + lg * 16) ^ s);
    }
#pragma unroll
    for (int fn = 0; fn < 8; ++fn) {
        int c = wn * 128 + fn * 16 + lr;
        int s = (c & 7) << 4;
#pragma unroll
        for (int kk = 0; kk < 2; ++kk)
            b_off[kk][fn] = 16384 + c * 128 + ((kk * 64 + lg * 16) ^ s);
    }

    for (int kt = 0; kt < F_IN / 64; ++kt) {
        // B: async global->LDS
#pragma unroll
        for (int j = 0; j < 4; ++j) {
            __builtin_amdgcn_global_load_lds(
                (const __attribute__((address_space(1))) unsigned*)(const void*)(gsrc[j] + (long)kt * 128),
                (__attribute__((address_space(3))) unsigned*)(void*)ldst[j], 16, 0, 0);
        }
        // A: fp32 load -> bf16 -> swizzled LDS write
        float4 av0 = *reinterpret_cast<const float4*>(aptr + kt * 64 + 0);
        float4 av1 = *reinterpret_cast<const float4*>(aptr + kt * 64 + 4);
        float4 av2 = *reinterpret_cast<const float4*>(aptr + kt * 64 + 8);
        float4 av3 = *reinterpret_cast<const float4*>(aptr + kt * 64 + 12);
        bf16x8 p0, p1;
        p0[0] = (__bf16)av0.x; p0[1] = (__bf16)av0.y; p0[2] = (__bf16)av0.z; p0[3] = (__bf16)av0.w;
        p0[4] = (__bf16)av1.x; p0[5] = (__bf16)av1.y; p0[6] = (__bf16)av1.z; p0[7] = (__bf16)av1.w;
        p1[0] = (__bf16)av2.x; p1[1] = (__bf16)av2.y; p1[2] = (__bf16)av2.z; p1[3] = (__bf16)av2.w;
        p1[4] = (__bf16)av3.x; p1[5] = (__bf16)av3.y; p1[6] = (__bf16)av3.z; p1[7] = (__bf16)av3.w;
        *reinterpret_cast<bf16x8*>(adst0) = p0;
        *reinterpret_cast<bf16x8*>(adst1) = p1;
        __syncthreads();  // drains vmcnt (B) + lgkm (A writes)
#pragma unroll
        for (int kk = 0; kk < 2; ++kk) {
            bf16x8 va[2], vb[8];
#pragma unroll
            for (int fm = 0; fm < 2; ++fm)
                va[fm] = *reinterpret_cast<const bf16x8*>(smem + a_off[fm][kk]);
#pragma unroll
            for (int fn = 0; fn < 8; ++fn)
                vb[fn] = *reinterpret_cast<const bf16x8*>(smem + b_off[kk][fn]);
#pragma unroll
            for (int fm = 0; fm < 2; ++fm)
#pragma unroll
                for (int fn = 0; fn < 8; ++fn)
                    acc[fm][fn] = __builtin_amdgcn_mfma_f32_16x16x32_bf16(
                        va[fm], vb[fn], acc[fm][fn], 0, 0, 0);
        }
        __syncthreads();
    }

    // epilogue: C/D col=lane&15, row=(lane>>4)*4+j
#pragma unroll
    for (int fn = 0; fn < 8; ++fn) {
        int col = wn * 128 + fn * 16 + lr;
        float bvv = (col >= HID) ? bias[col - HID] : 0.f;
#pragma unroll
        for (int fm = 0; fm < 2; ++fm) {
            long row = m0 + wm * 32 + fm * 16 + lg * 4;
#pragma unroll
            for (int j2 = 0; j2 < 4; ++j2)
                H[(row + j2) * 256 + col] = (__bf16)(acc[fm][fn][j2] + bvv);
        }
    }
}

// ---------------- GEMM2 (bf16 A): H[Mp][128] = A[Mp][128] @ Bt[128][128]^T ----------------
template <int NT, int NH>
__global__ __launch_bounds__(256) void gemm_mfma(const __bf16* __restrict__ A,
                                                 const __bf16* __restrict__ Bt,
                                                 const float* __restrict__ bias,
                                                 __bf16* __restrict__ H, int K) {
    __shared__ char smem[24576];
    const int tid = threadIdx.x;
    const int w = tid >> 6, l = tid & 63;
    const int lr = l & 15, lg = l >> 4;
    const long m0 = (long)blockIdx.x * 128;
    const int n0 = blockIdx.y * 64;
    const long Kb = (long)K * 2;

    f32x4 acc[2][4] = {};

    int a_off[2][2], b_off[2][4];
#pragma unroll
    for (int fm = 0; fm < 2; ++fm) {
        int r = w * 32 + fm * 16 + lr;
        int s = (r & 7) << 4;
#pragma unroll
        for (int kk = 0; kk < 2; ++kk)
            a_off[fm][kk] = r * 128 + ((kk * 64 + lg * 16) ^ s);
    }
#pragma unroll
    for (int fn = 0; fn < 4; ++fn) {
        int c = fn * 16 + lr;
        int s = (c & 7) << 4;
#pragma unroll
        for (int kk = 0; kk < 2; ++kk)
            b_off[kk][fn] = 16384 + c * 128 + ((kk * 64 + lg * 16) ^ s);
    }

    const char* gsrc[6];
    char* ldst[6];
#pragma unroll
    for (int j = 0; j < 6; ++j) {
        int p = (w * 6 + j) * 1024 + l * 16;
        ldst[j] = smem + (w * 6 + j) * 1024;
        if (p < 16384) {
            int row = p >> 7;
            int loff = (p & 127) ^ ((row & 7) << 4);
            gsrc[j] = (const char*)A + (m0 + row) * Kb + loff;
        } else {
            int q = p - 16384;
            int c = q >> 7;
            int loff = (q & 127) ^ ((c & 7) << 4);
            gsrc[j] = (const char*)Bt + (long)(n0 + c) * Kb + loff;
        }
    }

    const int nk = K >> 6;
    for (int kt = 0; kt < nk; ++kt) {
#pragma unroll
        for (int j = 0; j < 6; ++j) {
            __builtin_amdgcn_global_load_lds(
                (const __attribute__((address_space(1))) unsigned*)(const void*)(gsrc[j] + (long)kt * 128),
                (__attribute__((address_space(3))) unsigned*)(void*)ldst[j], 16, 0, 0);
        }
        __syncthreads();
#pragma unroll
        for (int kk = 0; kk < 2; ++kk) {
            bf16x8 av[2], bv[4];
#pragma unroll
            for (int fm = 0; fm < 2; ++fm)
                av[fm] = *reinterpret_cast<const bf16x8*>(smem + a_off[fm][kk]);
#pragma unroll
            for (int fn = 0; fn < 4; ++fn)
                bv[fn] = *reinterpret_cast<const bf16x8*>(smem + b_off[kk][fn]);
#pragma unroll
            for (int fm = 0; fm < 2; ++fm)
#pragma unroll
                for (int fn = 0; fn < 4; ++fn)
                    acc[fm][fn] = __builtin_amdgcn_mfma_f32_16x16x32_bf16(
                        av[fm], bv[fn], acc[fm][fn], 0, 0, 0);
        }
        __syncthreads();
    }

#pragma unroll
    for (int fn = 0; fn < 4; ++fn) {
        int col = n0 + fn * 16 + lr;
        float bvv = (col >= NH) ? bias[col - NH] : 0.f;
#pragma unroll
        for (int fm = 0; fm < 2; ++fm) {
            long row = m0 + w * 32 + fm * 16 + lg * 4;
#pragma unroll
            for (int j2 = 0; j2 < 4; ++j2)
                H[(row + j2) * NT + col] = (__bf16)(acc[fm][fn][j2] + bvv);
        }
    }
}

// ---------------- gather F=128: quarter-wave, 16 edges in flight per wave ----------------
__global__ __launch_bounds__(256) void gather128_kernel(const int* __restrict__ rowptr,
                                                        const int* __restrict__ cnt,
                                                        const uint2* __restrict__ epk,
                                                        const unsigned short* __restrict__ Hb,
                                                        __bf16* __restrict__ outb, int n) {
    int wid = (blockIdx.x * 256 + threadIdx.x) >> 6;
    int l = threadIdx.x & 63;
    if (wid >= n) return;
    const int len = cnt[wid];
    const int s0 = rowptr[wid] - len;  // rowptr holds end-offsets after fill
    const int li = l & 15, q = l >> 4;

    int sv = 0;
    float nv = 0.f;
    if (l < len) {
        uint2 p = epk[s0 + l];
        sv = (int)p.x;
        nv = __uint_as_float(p.y);
    }
    const int m = len < 64 ? len : 64;
    const int T = (m + 3) >> 2;

    float a[8] = {};
#pragma unroll 4
    for (int t = 0; t < T; ++t) {
        int e = 4 * t + q;
        int s = __shfl(sv, e);
        float nr = __shfl(nv, e);
        uint4 v = *reinterpret_cast<const uint4*>(Hb + (size_t)s * 256 + 8 * li);
        a[0] = fmaf(nr, lo16(v.x), a[0]);
        a[1] = fmaf(nr, hi16(v.x), a[1]);
        a[2] = fmaf(nr, lo16(v.y), a[2]);
        a[3] = fmaf(nr, hi16(v.y), a[3]);
        a[4] = fmaf(nr, lo16(v.z), a[4]);
        a[5] = fmaf(nr, hi16(v.z), a[5]);
        a[6] = fmaf(nr, lo16(v.w), a[6]);
        a[7] = fmaf(nr, hi16(v.w), a[7]);
    }
    for (int k = 64; k < len; ++k) {  // tail: essentially never (Poisson(16))
        if (q == 0) {
            uint2 p = epk[s0 + k];
            int s = (int)p.x;
            float nr = __uint_as_float(p.y);
            uint4 v = *reinterpret_cast<const uint4*>(Hb + (size_t)s * 256 + 8 * li);
            a[0] = fmaf(nr, lo16(v.x), a[0]);
            a[1] = fmaf(nr, hi16(v.x), a[1]);
            a[2] = fmaf(nr, lo16(v.y), a[2]);
            a[3] = fmaf(nr, hi16(v.y), a[3]);
            a[4] = fmaf(nr, lo16(v.z), a[4]);
            a[5] = fmaf(nr, hi16(v.z), a[5]);
            a[6] = fmaf(nr, lo16(v.w), a[6]);
            a[7] = fmaf(nr, hi16(v.w), a[7]);
        }
    }
#pragma unroll
    for (int i = 0; i < 8; ++i) {
        a[i] += __shfl_xor(a[i], 16);
        a[i] += __shfl_xor(a[i], 32);
    }
    if (l < 16) {
        uint4 rv = *reinterpret_cast<const uint4*>(Hb + (size_t)wid * 256 + 128 + 8 * l);
        float r[8] = {lo16(rv.x), hi16(rv.x), lo16(rv.y), hi16(rv.y),
                      lo16(rv.z), hi16(rv.z), lo16(rv.w), hi16(rv.w)};
        union { uint4 v; __bf16 b[8]; } o;
#pragma unroll
        for (int i = 0; i < 8; ++i) o.b[i] = (__bf16)fmaxf(a[i] + r[i], 0.f);
        *reinterpret_cast<uint4*>(outb + (size_t)wid * 128 + 8 * l) = o.v;
    }
}

// ---------------- gather F=64: quarter-wave, fp32 out ----------------
__global__ __launch_bounds__(256) void gather64_kernel(const int* __restrict__ rowptr,
                                                       const int* __restrict__ cnt,
                                                       const uint2* __restrict__ epk,
                                                       const unsigned short* __restrict__ Hb,
                                                       float* __restrict__ out, int n) {
    int wid = (blockIdx.x * 256 + threadIdx.x) >> 6;
    int l = threadIdx.x & 63;
    if (wid >= n) return;
    const int len = cnt[wid];
    const int s0 = rowptr[wid] - len;
    const int li = l & 15, q = l >> 4;

    int sv = 0;
    float nv = 0.f;
    if (l < len) {
        uint2 p = epk[s0 + l];
        sv = (int)p.x;
        nv = __uint_as_float(p.y);
    }
    const int m = len < 64 ? len : 64;
    const int T = (m + 3) >> 2;

    float a[4] = {};
#pragma unroll 4
    for (int t = 0; t < T; ++t) {
        int e = 4 * t + q;
        int s = __shfl(sv, e);
        float nr = __shfl(nv, e);
        uint2 v = *reinterpret_cast<const uint2*>(Hb + (size_t)s * 128 + 4 * li);
        a[0] = fmaf(nr, lo16(v.x), a[0]);
        a[1] = fmaf(nr, hi16(v.x), a[1]);
        a[2] = fmaf(nr, lo16(v.y), a[2]);
        a[3] = fmaf(nr, hi16(v.y), a[3]);
    }
    for (int k = 64; k < len; ++k) {
        if (q == 0) {
            uint2 p = epk[s0 + k];
            int s = (int)p.x;
            float nr = __uint_as_float(p.y);
            uint2 v = *reinterpret_cast<const uint2*>(Hb + (size_t)s * 128 + 4 * li);
            a[0] = fmaf(nr, lo16(v.x), a[0]);
            a[1] = fmaf(nr, hi16(v.x), a[1]);
            a[2] = fmaf(nr, lo16(v.y), a[2]);
            a[3] = fmaf(nr, hi16(v.y), a[3]);
        }
    }
#pragma unroll
    for (int i = 0; i < 4; ++i) {
        a[i] += __shfl_xor(a[i], 16);
        a[i] += __shfl_xor(a[i], 32);
    }
    if (l < 16) {
        uint2 rv = *reinterpret_cast<const uint2*>(Hb + (size_t)wid * 128 + 64 + 4 * l);
        float4 o;
        o.x = fmaxf(a[0] + lo16(rv.x), 0.f);
        o.y = fmaxf(a[1] + hi16(rv.x), 0.f);
        o.z = fmaxf(a[2] + lo16(rv.y), 0.f);
        o.w = fmaxf(a[3] + hi16(rv.y), 0.f);
        *reinterpret_cast<float4*>(out + (size_t)wid * 64 + 4 * l) = o;
    }
}

extern "C" void kernel_launch(void* const* d_in, const int* in_sizes, int n_in,
                              void* d_out, int out_size, void* d_ws, size_t ws_size,
                              hipStream_t stream) {
    const float* x   = (const float*)d_in[0];
    const float* W1i = (const float*)d_in[1];
    const float* W1r = (const float*)d_in[2];
    const float* b1  = (const float*)d_in[3];
    const float* W2i = (const float*)d_in[4];
    const float* W2r = (const float*)d_in[5];
    const float* b2  = (const float*)d_in[6];
    const int*   ei  = (const int*)d_in[7];

    const int E = in_sizes[7] / 2;
    const int M = in_sizes[0] / F_IN;  // 40000
    const int* src = ei;
    const int* dst = ei + E;

    char* w = (char*)d_ws;
    int*    cnt    = (int*)w;            w += 40960 * 4;
    int*    rowptr = (int*)w;            w += 40960 * 4;
    float*  dinv   = (float*)w;          w += 40960 * 4;
    int*    bsum   = (int*)w;            w += 4096;
    uint2*  epk    = (uint2*)w;          w += (size_t)E * 8;
    __bf16* W1t    = (__bf16*)w;         w += 256 * 512 * 2;
    __bf16* W2t    = (__bf16*)w;         w += 128 * 128 * 2;
    __bf16* H1b    = (__bf16*)w;         w += (size_t)MPAD * 256 * 2;  // 20.5MB
    __bf16* out1b  = (__bf16*)w;         w += (size_t)MPAD * 128 * 2;  // 10.25MB
    __bf16* H2b    = (__bf16*)w;         w += (size_t)MPAD * 128 * 2;  // 10.25MB
    float*  outp   = (float*)d_out;

    const int nb = (M + 1023) / 1024;

    // ---- CSR build ----
    hipMemsetAsync(cnt, 0, (size_t)M * sizeof(int), stream);
    count_kernel<<<(E + 255) / 256, 256, 0, stream>>>(dst, cnt, E);
    dinv_kernel<<<(M + 255) / 256, 256, 0, stream>>>(cnt, dinv, M);
    scan1_kernel<<<nb, 1024, 0, stream>>>(cnt, rowptr, bsum, M);
    scan2_kernel<<<1, 64, 0, stream>>>(bsum, nb);
    scan3_kernel<<<nb, 1024, 0, stream>>>(rowptr, bsum, M);
    fill_kernel<<<(E + 255) / 256, 256, 0, stream>>>(src, dst, rowptr, dinv, epk, E);

    // ---- weight prep ----
    prep_w_kernel<<<256, 256, 0, stream>>>(W1i, W1r, W1t, F_IN, HID);
    prep_w_kernel<<<128, 256, 0, stream>>>(W2i, W2r, W2t, HID, NCLS);

    // ---- layer 1 (cast fused into GEMM) ----
    gemm1_kernel<<<MPAD / 128, 512, 0, stream>>>(x, W1t, b1, H1b, M);
    gather128_kernel<<<(M * 64 + 255) / 256, 256, 0, stream>>>(
        rowptr, cnt, epk, (const unsigned short*)H1b, out1b, M);

    // ---- layer 2 ----
    gemm_mfma<128, 64><<<dim3(MPAD / 128, 2), 256, 0, stream>>>(out1b, W2t, b2, H2b, HID);
    gather64_kernel<<<(M * 64 + 255) / 256, 256, 0, stream>>>(
        rowptr, cnt, epk, (const unsigned short*)H2b, outp, M);
}

// Round 7
// 160.658 us; speedup vs baseline: 4.4437x; 1.0041x over previous
//
#include <hip/hip_runtime.h>

// ARMAConv x2 GNN: N=40000, E=640000, F_IN=512, HID=128, NCLS=64
#define F_IN 512
#define HID 128
#define NCLS 64
#define MPAD 40064  // 313 * 128

typedef __bf16 bf16x8 __attribute__((ext_vector_type(8)));
typedef float f32x4 __attribute__((ext_vector_type(4)));

__device__ __forceinline__ float lo16(unsigned u) {
    unsigned x = u << 16;
    float f;
    __builtin_memcpy(&f, &x, 4);
    return f;
}
__device__ __forceinline__ float hi16(unsigned u) {
    unsigned x = u & 0xffff0000u;
    float f;
    __builtin_memcpy(&f, &x, 4);
    return f;
}

// ---------------- degree count ----------------
__global__ __launch_bounds__(256) void count_kernel(const int* __restrict__ dst,
                                                    int* __restrict__ cnt, int E) {
    int i = blockIdx.x * 256 + threadIdx.x;
    if (i < E) atomicAdd(&cnt[dst[i]], 1);
}

// ---------------- scan stage 1 (+ fused dinv) ----------------
__global__ __launch_bounds__(1024) void scan1_kernel(const int* __restrict__ cnt,
                                                     int* __restrict__ rowptr,
                                                     int* __restrict__ bsum,
                                                     float* __restrict__ dinv, int n) {
    __shared__ int s[1024];
    int tid = threadIdx.x;
    int i = blockIdx.x * 1024 + tid;
    int v = (i < n) ? cnt[i] : 0;
    if (i < n) dinv[i] = v > 0 ? rsqrtf((float)v) : 0.f;
    s[tid] = v;
    __syncthreads();
    for (int off = 1; off < 1024; off <<= 1) {
        int t = (tid >= off) ? s[tid - off] : 0;
        __syncthreads();
        s[tid] += t;
        __syncthreads();
    }
    if (i < n) rowptr[i] = s[tid] - v;  // exclusive within block
    if (tid == 1023) bsum[blockIdx.x] = s[1023];
}

// ---------------- scan stage 2+3 fused: each block prefixes bsum itself ----------------
__global__ __launch_bounds__(1024) void scan23_kernel(int* __restrict__ rowptr,
                                                      const int* __restrict__ bsum, int n) {
    __shared__ int off_s;
    if (threadIdx.x == 0) {
        int run = 0;
        for (int b = 0; b < (int)blockIdx.x; ++b) run += bsum[b];
        off_s = run;
    }
    __syncthreads();
    int i = blockIdx.x * 1024 + threadIdx.x;
    if (i < n) rowptr[i] += off_s;
}

// ---------------- CSR fill: bump rowptr in place (becomes end-offsets) ----------------
__global__ __launch_bounds__(256) void fill_kernel(const int* __restrict__ src,
                                                   const int* __restrict__ dst,
                                                   int* __restrict__ rowptr,
                                                   const float* __restrict__ dinv,
                                                   uint2* __restrict__ epk, int E) {
    int e = blockIdx.x * 256 + threadIdx.x;
    if (e < E) {
        int s = src[e];
        int d = dst[e];
        int pos = atomicAdd(&rowptr[d], 1);
        float nr = dinv[s] * dinv[d];
        unsigned nu;
        __builtin_memcpy(&nu, &nr, 4);
        epk[pos] = make_uint2((unsigned)s, nu);
    }
}

// ---------------- weight prep (both layers in one launch) ----------------
__global__ __launch_bounds__(256) void prep_w_kernel(const float* __restrict__ W1i,
                                                     const float* __restrict__ W1r,
                                                     const float* __restrict__ W2i,
                                                     const float* __restrict__ W2r,
                                                     __bf16* __restrict__ W1t,
                                                     __bf16* __restrict__ W2t) {
    int n = blockIdx.x;
    if (n < 256) {  // layer 1: Wt[n][k], k<512
        const float* Wsrc = (n < HID) ? W1i : W1r;
        int c = (n < HID) ? n : n - HID;
        for (int k = threadIdx.x; k < F_IN; k += 256)
            W1t[(long)n * F_IN + k] = (__bf16)Wsrc[(long)k * HID + c];
    } else {        // layer 2: Wt[m][k], k<128
        int m = n - 256;
        const float* Wsrc = (m < NCLS) ? W2i : W2r;
        int c = (m < NCLS) ? m : m - NCLS;
        for (int k = threadIdx.x; k < HID; k += 256)
            W2t[(long)m * HID + k] = (__bf16)Wsrc[(long)k * NCLS + c];
    }
}

// ---------------- GEMM1 fused-cast, reg-staged prefetch, raw-barrier pipeline ----------
// H[Mp][256] = bf16(A_f32[M][512]) @ Bt[256][512]^T (+bias cols>=HID).
// 64x256 tile, 512 thr (8 waves: 4M x 2N), BK=64, LDS 40KB single buffer.
// Prefetch next K-tile into REGISTERS (thread-private => barriers need lgkmcnt only,
// no vmcnt drain => loads stay in flight across barriers). XOR swizzle (row&7)<<4
// applied on ds_write AND ds_read (both-sides rule).
__global__ __launch_bounds__(512) void gemm1_kernel(const float* __restrict__ A,
                                                    const __bf16* __restrict__ Bt,
                                                    const float* __restrict__ bias,
                                                    __bf16* __restrict__ H, int M) {
    __shared__ char smem[40960];  // A [64 rows][128B] @0 (8KB); B [256 cols][128B] @8192 (32KB)
    const int tid = threadIdx.x;
    const int w = tid >> 6, l = tid & 63;
    const int wm = w >> 1, wn = w & 1;   // 4M x 2N wave grid
    const int lr = l & 15, lg = l >> 4;
    const long m0 = (long)blockIdx.x * 64;

    f32x4 acc[8] = {};

    // A-stage: thread covers row=tid>>3 (0..63), 8 fp32 at k0=(tid&7)*8
    const int ar = tid >> 3;
    const int ak0 = (tid & 7) << 3;
    long arow = m0 + ar;
    if (arow >= M) arow = M - 1;  // tail clamp (rows >= M never consumed)
    const float* aptr = A + arow * F_IN + ak0;
    char* adst = smem + ar * 128 + ((ak0 * 2) ^ ((ar & 7) << 4));

    // B-stage: 4 chunks of 16B; linear global read, swizzled LDS write
    const char* bsrc[4];
    char* bdst[4];
#pragma unroll
    for (int j = 0; j < 4; ++j) {
        int q = (tid + j * 512) * 16;  // byte in [0, 32768)
        int c = q >> 7, off = q & 127;
        bsrc[j] = (const char*)Bt + (long)c * (F_IN * 2) + off;
        bdst[j] = smem + 8192 + c * 128 + (off ^ ((c & 7) << 4));
    }

    // reader offsets
    int a_off[2], b_off[2][8];
    {
        int r = wm * 16 + lr, s = (r & 7) << 4;
#pragma unroll
        for (int kk = 0; kk < 2; ++kk) a_off[kk] = r * 128 + ((kk * 64 + lg * 16) ^ s);
    }
#pragma unroll
    for (int fn = 0; fn < 8; ++fn) {
        int c = wn * 128 + fn * 16 + lr, s = (c & 7) << 4;
#pragma unroll
        for (int kk = 0; kk < 2; ++kk)
            b_off[kk][fn] = 8192 + c * 128 + ((kk * 64 + lg * 16) ^ s);
    }

    // prologue: tile 0 -> regs
    float4 a0 = *reinterpret_cast<const float4*>(aptr);
    float4 a1 = *reinterpret_cast<const float4*>(aptr + 4);
    uint4 br[4];
#pragma unroll
    for (int j = 0; j < 4; ++j) br[j] = *reinterpret_cast<const uint4*>(bsrc[j]);

#pragma unroll
    for (int kt = 0; kt < F_IN / 64; ++kt) {
        // stage regs -> LDS (compiler inserts vmcnt wait for the reg loads)
        bf16x8 p;
        p[0] = (__bf16)a0.x; p[1] = (__bf16)a0.y; p[2] = (__bf16)a0.z; p[3] = (__bf16)a0.w;
        p[4] = (__bf16)a1.x; p[5] = (__bf16)a1.y; p[6] = (__bf16)a1.z; p[7] = (__bf16)a1.w;
        *reinterpret_cast<bf16x8*>(adst) = p;
#pragma unroll
        for (int j = 0; j < 4; ++j) *reinterpret_cast<uint4*>(bdst[j]) = br[j];
        asm volatile("s_waitcnt lgkmcnt(0)" ::: "memory");  // writes visible
        __builtin_amdgcn_s_barrier();
        __builtin_amdgcn_sched_barrier(0);
        // prefetch next tile into regs (stays in flight across barriers: no vmcnt drain)
        if (kt + 1 < F_IN / 64) {
            a0 = *reinterpret_cast<const float4*>(aptr + (kt + 1) * 64);
            a1 = *reinterpret_cast<const float4*>(aptr + (kt + 1) * 64 + 4);
#pragma unroll
            for (int j = 0; j < 4; ++j)
                br[j] = *reinterpret_cast<const uint4*>(bsrc[j] + (kt + 1) * 128);
        }
        // compute current tile
#pragma unroll
        for (int kk = 0; kk < 2; ++kk) {
            bf16x8 va = *reinterpret_cast<const bf16x8*>(smem + a_off[kk]);
#pragma unroll
            for (int fn = 0; fn < 8; ++fn) {
                bf16x8 vb = *reinterpret_cast<const bf16x8*>(smem + b_off[kk][fn]);
                acc[fn] = __builtin_amdgcn_mfma_f32_16x16x32_bf16(va, vb, acc[fn], 0, 0, 0);
            }
        }
        __builtin_amdgcn_sched_barrier(0);  // reads complete (consumed) before barrier
        __builtin_amdgcn_s_barrier();       // safe to overwrite LDS next iter
    }

    // epilogue: C/D col=lane&15, row=(lane>>4)*4+j
#pragma unroll
    for (int fn = 0; fn < 8; ++fn) {
        int col = wn * 128 + fn * 16 + lr;
        float bvv = (col >= HID) ? bias[col - HID] : 0.f;
        long row = m0 + wm * 16 + lg * 4;
#pragma unroll
        for (int j2 = 0; j2 < 4; ++j2)
            H[(row + j2) * 256 + col] = (__bf16)(acc[fn][j2] + bvv);
    }
}

// ---------------- GEMM2 (bf16 A): H[Mp][128] = A[Mp][128] @ Bt[128][128]^T ----------------
template <int NT, int NH>
__global__ __launch_bounds__(256) void gemm_mfma(const __bf16* __restrict__ A,
                                                 const __bf16* __restrict__ Bt,
                                                 const float* __restrict__ bias,
                                                 __bf16* __restrict__ H, int K) {
    __shared__ char smem[24576];
    const int tid = threadIdx.x;
    const int w = tid >> 6, l = tid & 63;
    const int lr = l & 15, lg = l >> 4;
    const long m0 = (long)blockIdx.x * 128;
    const int n0 = blockIdx.y * 64;
    const long Kb = (long)K * 2;

    f32x4 acc[2][4] = {};

    int a_off[2][2], b_off[2][4];
#pragma unroll
    for (int fm = 0; fm < 2; ++fm) {
        int r = w * 32 + fm * 16 + lr;
        int s = (r & 7) << 4;
#pragma unroll
        for (int kk = 0; kk < 2; ++kk)
            a_off[fm][kk] = r * 128 + ((kk * 64 + lg * 16) ^ s);
    }
#pragma unroll
    for (int fn = 0; fn < 4; ++fn) {
        int c = fn * 16 + lr;
        int s = (c & 7) << 4;
#pragma unroll
        for (int kk = 0; kk < 2; ++kk)
            b_off[kk][fn] = 16384 + c * 128 + ((kk * 64 + lg * 16) ^ s);
    }

    const char* gsrc[6];
    char* ldst[6];
#pragma unroll
    for (int j = 0; j < 6; ++j) {
        int p = (w * 6 + j) * 1024 + l * 16;
        ldst[j] = smem + (w * 6 + j) * 1024;
        if (p < 16384) {
            int row = p >> 7;
            int loff = (p & 127) ^ ((row & 7) << 4);
            gsrc[j] = (const char*)A + (m0 + row) * Kb + loff;
        } else {
            int q = p - 16384;
            int c = q >> 7;
            int loff = (q & 127) ^ ((c & 7) << 4);
            gsrc[j] = (const char*)Bt + (long)(n0 + c) * Kb + loff;
        }
    }

    const int nk = K >> 6;
    for (int kt = 0; kt < nk; ++kt) {
#pragma unroll
        for (int j = 0; j < 6; ++j) {
            __builtin_amdgcn_global_load_lds(
                (const __attribute__((address_space(1))) unsigned*)(const void*)(gsrc[j] + (long)kt * 128),
                (__attribute__((address_space(3))) unsigned*)(void*)ldst[j], 16, 0, 0);
        }
        __syncthreads();
#pragma unroll
        for (int kk = 0; kk < 2; ++kk) {
            bf16x8 av[2], bv[4];
#pragma unroll
            for (int fm = 0; fm < 2; ++fm)
                av[fm] = *reinterpret_cast<const bf16x8*>(smem + a_off[fm][kk]);
#pragma unroll
            for (int fn = 0; fn < 4; ++fn)
                bv[fn] = *reinterpret_cast<const bf16x8*>(smem + b_off[kk][fn]);
#pragma unroll
            for (int fm = 0; fm < 2; ++fm)
#pragma unroll
                for (int fn = 0; fn < 4; ++fn)
                    acc[fm][fn] = __builtin_amdgcn_mfma_f32_16x16x32_bf16(
                        av[fm], bv[fn], acc[fm][fn], 0, 0, 0);
        }
        __syncthreads();
    }

#pragma unroll
    for (int fn = 0; fn < 4; ++fn) {
        int col = n0 + fn * 16 + lr;
        float bvv = (col >= NH) ? bias[col - NH] : 0.f;
#pragma unroll
        for (int fm = 0; fm < 2; ++fm) {
            long row = m0 + w * 32 + fm * 16 + lg * 4;
#pragma unroll
            for (int j2 = 0; j2 < 4; ++j2)
                H[(row + j2) * NT + col] = (__bf16)(acc[fm][fn][j2] + bvv);
        }
    }
}

// ---------------- gather F=128: quarter-wave, 16 edges in flight per wave ----------------
__global__ __launch_bounds__(256) void gather128_kernel(const int* __restrict__ rowptr,
                                                        const int* __restrict__ cnt,
                                                        const uint2* __restrict__ epk,
                                                        const unsigned short* __restrict__ Hb,
                                                        __bf16* __restrict__ outb, int n) {
    int wid = (blockIdx.x * 256 + threadIdx.x) >> 6;
    int l = threadIdx.x & 63;
    if (wid >= n) return;
    const int len = cnt[wid];
    const int s0 = rowptr[wid] - len;  // rowptr holds end-offsets after fill
    const int li = l & 15, q = l >> 4;

    int sv = 0;
    float nv = 0.f;
    if (l < len) {
        uint2 p = epk[s0 + l];
        sv = (int)p.x;
        nv = __uint_as_float(p.y);
    }
    const int m = len < 64 ? len : 64;
    const int T = (m + 3) >> 2;

    float a[8] = {};
#pragma unroll 4
    for (int t = 0; t < T; ++t) {
        int e = 4 * t + q;
        int s = __shfl(sv, e);
        float nr = __shfl(nv, e);
        uint4 v = *reinterpret_cast<const uint4*>(Hb + (size_t)s * 256 + 8 * li);
        a[0] = fmaf(nr, lo16(v.x), a[0]);
        a[1] = fmaf(nr, hi16(v.x), a[1]);
        a[2] = fmaf(nr, lo16(v.y), a[2]);
        a[3] = fmaf(nr, hi16(v.y), a[3]);
        a[4] = fmaf(nr, lo16(v.z), a[4]);
        a[5] = fmaf(nr, hi16(v.z), a[5]);
        a[6] = fmaf(nr, lo16(v.w), a[6]);
        a[7] = fmaf(nr, hi16(v.w), a[7]);
    }
    for (int k = 64; k < len; ++k) {  // tail: essentially never (Poisson(16))
        if (q == 0) {
            uint2 p = epk[s0 + k];
            int s = (int)p.x;
            float nr = __uint_as_float(p.y);
            uint4 v = *reinterpret_cast<const uint4*>(Hb + (size_t)s * 256 + 8 * li);
            a[0] = fmaf(nr, lo16(v.x), a[0]);
            a[1] = fmaf(nr, hi16(v.x), a[1]);
            a[2] = fmaf(nr, lo16(v.y), a[2]);
            a[3] = fmaf(nr, hi16(v.y), a[3]);
            a[4] = fmaf(nr, lo16(v.z), a[4]);
            a[5] = fmaf(nr, hi16(v.z), a[5]);
            a[6] = fmaf(nr, lo16(v.w), a[6]);
            a[7] = fmaf(nr, hi16(v.w), a[7]);
        }
    }
#pragma unroll
    for (int i = 0; i < 8; ++i) {
        a[i] += __shfl_xor(a[i], 16);
        a[i] += __shfl_xor(a[i], 32);
    }
    if (l < 16) {
        uint4 rv = *reinterpret_cast<const uint4*>(Hb + (size_t)wid * 256 + 128 + 8 * l);
        float r[8] = {lo16(rv.x), hi16(rv.x), lo16(rv.y), hi16(rv.y),
                      lo16(rv.z), hi16(rv.z), lo16(rv.w), hi16(rv.w)};
        union { uint4 v; __bf16 b[8]; } o;
#pragma unroll
        for (int i = 0; i < 8; ++i) o.b[i] = (__bf16)fmaxf(a[i] + r[i], 0.f);
        *reinterpret_cast<uint4*>(outb + (size_t)wid * 128 + 8 * l) = o.v;
    }
}

// ---------------- gather F=64: quarter-wave, fp32 out ----------------
__global__ __launch_bounds__(256) void gather64_kernel(const int* __restrict__ rowptr,
                                                       const int* __restrict__ cnt,
                                                       const uint2* __restrict__ epk,
                                                       const unsigned short* __restrict__ Hb,
                                                       float* __restrict__ out, int n) {
    int wid = (blockIdx.x * 256 + threadIdx.x) >> 6;
    int l = threadIdx.x & 63;
    if (wid >= n) return;
    const int len = cnt[wid];
    const int s0 = rowptr[wid] - len;
    const int li = l & 15, q = l >> 4;

    int sv = 0;
    float nv = 0.f;
    if (l < len) {
        uint2 p = epk[s0 + l];
        sv = (int)p.x;
        nv = __uint_as_float(p.y);
    }
    const int m = len < 64 ? len : 64;
    const int T = (m + 3) >> 2;

    float a[4] = {};
#pragma unroll 4
    for (int t = 0; t < T; ++t) {
        int e = 4 * t + q;
        int s = __shfl(sv, e);
        float nr = __shfl(nv, e);
        uint2 v = *reinterpret_cast<const uint2*>(Hb + (size_t)s * 128 + 4 * li);
        a[0] = fmaf(nr, lo16(v.x), a[0]);
        a[1] = fmaf(nr, hi16(v.x), a[1]);
        a[2] = fmaf(nr, lo16(v.y), a[2]);
        a[3] = fmaf(nr, hi16(v.y), a[3]);
    }
    for (int k = 64; k < len; ++k) {
        if (q == 0) {
            uint2 p = epk[s0 + k];
            int s = (int)p.x;
            float nr = __uint_as_float(p.y);
            uint2 v = *reinterpret_cast<const uint2*>(Hb + (size_t)s * 128 + 4 * li);
            a[0] = fmaf(nr, lo16(v.x), a[0]);
            a[1] = fmaf(nr, hi16(v.x), a[1]);
            a[2] = fmaf(nr, lo16(v.y), a[2]);
            a[3] = fmaf(nr, hi16(v.y), a[3]);
        }
    }
#pragma unroll
    for (int i = 0; i < 4; ++i) {
        a[i] += __shfl_xor(a[i], 16);
        a[i] += __shfl_xor(a[i], 32);
    }
    if (l < 16) {
        uint2 rv = *reinterpret_cast<const uint2*>(Hb + (size_t)wid * 128 + 64 + 4 * l);
        float4 o;
        o.x = fmaxf(a[0] + lo16(rv.x), 0.f);
        o.y = fmaxf(a[1] + hi16(rv.x), 0.f);
        o.z = fmaxf(a[2] + lo16(rv.y), 0.f);
        o.w = fmaxf(a[3] + hi16(rv.y), 0.f);
        *reinterpret_cast<float4*>(out + (size_t)wid * 64 + 4 * l) = o;
    }
}

extern "C" void kernel_launch(void* const* d_in, const int* in_sizes, int n_in,
                              void* d_out, int out_size, void* d_ws, size_t ws_size,
                              hipStream_t stream) {
    const float* x   = (const float*)d_in[0];
    const float* W1i = (const float*)d_in[1];
    const float* W1r = (const float*)d_in[2];
    const float* b1  = (const float*)d_in[3];
    const float* W2i = (const float*)d_in[4];
    const float* W2r = (const float*)d_in[5];
    const float* b2  = (const float*)d_in[6];
    const int*   ei  = (const int*)d_in[7];

    const int E = in_sizes[7] / 2;
    const int M = in_sizes[0] / F_IN;  // 40000
    const int* src = ei;
    const int* dst = ei + E;

    char* w = (char*)d_ws;
    int*    cnt    = (int*)w;            w += 40960 * 4;
    int*    rowptr = (int*)w;            w += 40960 * 4;
    float*  dinv   = (float*)w;          w += 40960 * 4;
    int*    bsum   = (int*)w;            w += 4096;
    uint2*  epk    = (uint2*)w;          w += (size_t)E * 8;
    __bf16* W1t    = (__bf16*)w;         w += 256 * 512 * 2;
    __bf16* W2t    = (__bf16*)w;         w += 128 * 128 * 2;
    __bf16* H1b    = (__bf16*)w;         w += (size_t)MPAD * 256 * 2;  // 20.5MB
    __bf16* out1b  = (__bf16*)w;         w += (size_t)MPAD * 128 * 2;  // 10.25MB
    __bf16* H2b    = (__bf16*)w;         w += (size_t)MPAD * 128 * 2;  // 10.25MB
    float*  outp   = (float*)d_out;

    const int nb = (M + 1023) / 1024;

    // ---- CSR build ----
    hipMemsetAsync(cnt, 0, (size_t)M * sizeof(int), stream);
    count_kernel<<<(E + 255) / 256, 256, 0, stream>>>(dst, cnt, E);
    scan1_kernel<<<nb, 1024, 0, stream>>>(cnt, rowptr, bsum, dinv, M);
    scan23_kernel<<<nb, 1024, 0, stream>>>(rowptr, bsum, M);
    fill_kernel<<<(E + 255) / 256, 256, 0, stream>>>(src, dst, rowptr, dinv, epk, E);

    // ---- weight prep (both layers) ----
    prep_w_kernel<<<384, 256, 0, stream>>>(W1i, W1r, W2i, W2r, W1t, W2t);

    // ---- layer 1 (cast fused into GEMM) ----
    gemm1_kernel<<<MPAD / 64, 512, 0, stream>>>(x, W1t, b1, H1b, M);
    gather128_kernel<<<(M * 64 + 255) / 256, 256, 0, stream>>>(
        rowptr, cnt, epk, (const unsigned short*)H1b, out1b, M);

    // ---- layer 2 ----
    gemm_mfma<128, 64><<<dim3(MPAD / 128, 2), 256, 0, stream>>>(out1b, W2t, b2, H2b, HID);
    gather64_kernel<<<(M * 64 + 255) / 256, 256, 0, stream>>>(
        rowptr, cnt, epk, (const unsigned short*)H2b, outp, M);
}